// Round 3
// baseline (260.416 us; speedup 1.0000x reference)
//
#include <hip/hip_runtime.h>
#include <math.h>

#define IN_C 512
#define HID  64
#define OUTC 40

typedef __attribute__((ext_vector_type(8))) short bf16x8;
typedef __attribute__((ext_vector_type(4))) float f32x4;

// ---------------- histogram of dst ----------------
__global__ void k_hist(const int* __restrict__ dst, int E, int* __restrict__ cnt) {
    int i = blockIdx.x * blockDim.x + threadIdx.x;
    if (i < E) atomicAdd(&cnt[dst[i]], 1);
}

// ---------------- prefix scan (3 kernels) ----------------
__global__ void k_scan1(const int* __restrict__ cnt, int N,
                        int* __restrict__ rowptr, int* __restrict__ bsum) {
    __shared__ int s[256];
    int t = threadIdx.x;
    int i = blockIdx.x * 256 + t;
    int v = (i < N) ? cnt[i] : 0;
    int x = v;
    s[t] = x; __syncthreads();
    #pragma unroll
    for (int o = 1; o < 256; o <<= 1) {
        int y = (t >= o) ? s[t - o] : 0;
        __syncthreads();
        x += y; s[t] = x;
        __syncthreads();
    }
    if (i < N) rowptr[i] = x - v;          // exclusive
    if (t == 255) bsum[blockIdx.x] = x;    // block total
}

__global__ void k_scan2(const int* __restrict__ bsum, int nb, int* __restrict__ bpre) {
    __shared__ int s[256];
    int t = threadIdx.x;
    int v = (t < nb) ? bsum[t] : 0;
    int x = v;
    s[t] = x; __syncthreads();
    #pragma unroll
    for (int o = 1; o < 256; o <<= 1) {
        int y = (t >= o) ? s[t - o] : 0;
        __syncthreads();
        x += y; s[t] = x;
        __syncthreads();
    }
    bpre[t] = x - v;
}

__global__ void k_scan3(int* __restrict__ rowptr, const int* __restrict__ bpre,
                        const int* __restrict__ cnt, float* __restrict__ dinv,
                        int N, int E) {
    int i = blockIdx.x * blockDim.x + threadIdx.x;
    if (i < N) {
        rowptr[i] += bpre[i >> 8];
        dinv[i] = rsqrtf(1.0f + (float)cnt[i]);   // self-loop => deg >= 1
        if (i == 0) rowptr[N] = E;
    }
}

// ---------------- counting-sort fill ----------------
__global__ void k_fill(const int* __restrict__ src, const int* __restrict__ dst, int E,
                       const int* __restrict__ rowptr, int* __restrict__ fillc,
                       int* __restrict__ ssort) {
    int i = blockIdx.x * blockDim.x + threadIdx.x;
    if (i < E) {
        int d = dst[i];
        int p = rowptr[d] + atomicAdd(&fillc[d], 1);
        ssort[p] = src[i];
    }
}

// ---------------- W1 split to hi/lo bf16, transposed: WT[c][k] ----------------
__global__ void k_wsplit(const float* __restrict__ W,
                         ushort* __restrict__ hi, ushort* __restrict__ lo) {
    int i = blockIdx.x * blockDim.x + threadIdx.x;   // over 64*512
    if (i >= HID * IN_C) return;
    int c = i >> 9, k = i & 511;
    float v = W[(size_t)k * HID + c];
    uint ub = __float_as_uint(v);
    uint hb = ub & 0xFFFF0000u;
    float lf = v - __uint_as_float(hb);
    hi[i] = (ushort)(ub >> 16);
    lo[i] = (ushort)(__float_as_uint(lf) >> 16);
}

// ---------------- GEMM1 via split-bf16 MFMA, no LDS ----------------
// h1s[i][c] = dinv[i] * dot(x[i,:512], W1[:,c])
// Block: 64 rows, 4 waves; wave w: rows w*16..w*16+15, all 64 cols.
__global__ __launch_bounds__(256) void k_gemm1(const float* __restrict__ x,
                                               const ushort* __restrict__ WThi,
                                               const ushort* __restrict__ WTlo,
                                               const float* __restrict__ dinv,
                                               float* __restrict__ h1s, int N) {
    int t = threadIdx.x;
    int wid = t >> 6, lane = t & 63;
    int row0 = blockIdx.x * 64 + wid * 16;
    int lr = lane & 15;          // A row within tile / C col within tile
    int lko = lane >> 4;         // k-group (×8)
    int arow = row0 + lr; if (arow >= N) arow = N - 1;
    const float* xrow = x + (size_t)arow * IN_C + lko * 8;

    f32x4 acc[4] = {{0,0,0,0},{0,0,0,0},{0,0,0,0},{0,0,0,0}};

    for (int kt = 0; kt < IN_C; kt += 32) {
        float xv[8];
        *(float4*)&xv[0] = *(const float4*)(xrow + kt);
        *(float4*)&xv[4] = *(const float4*)(xrow + kt + 4);
        bf16x8 ahi, alo;
        #pragma unroll
        for (int j = 0; j < 8; ++j) {
            uint ub = __float_as_uint(xv[j]);
            float hf = __uint_as_float(ub & 0xFFFF0000u);
            float lf = xv[j] - hf;
            ahi[j] = (short)(ub >> 16);
            alo[j] = (short)(__float_as_uint(lf) >> 16);
        }
        const ushort* bbase = WThi + (size_t)lr * IN_C + kt + lko * 8;
        const ushort* bbasl = WTlo + (size_t)lr * IN_C + kt + lko * 8;
        #pragma unroll
        for (int ct = 0; ct < 4; ++ct) {
            bf16x8 bhi = *(const bf16x8*)(bbase + (size_t)ct * 16 * IN_C);
            bf16x8 blo = *(const bf16x8*)(bbasl + (size_t)ct * 16 * IN_C);
            acc[ct] = __builtin_amdgcn_mfma_f32_16x16x32_bf16(ahi, bhi, acc[ct], 0, 0, 0);
            acc[ct] = __builtin_amdgcn_mfma_f32_16x16x32_bf16(alo, bhi, acc[ct], 0, 0, 0);
            acc[ct] = __builtin_amdgcn_mfma_f32_16x16x32_bf16(ahi, blo, acc[ct], 0, 0, 0);
        }
    }

    // C/D layout (m89-verified): col = lane&15, row = (lane>>4)*4 + reg
    #pragma unroll
    for (int r = 0; r < 4; ++r) {
        int orow = row0 + lko * 4 + r;
        if (orow < N) {
            float dv = dinv[orow];
            #pragma unroll
            for (int ct = 0; ct < 4; ++ct)
                h1s[(size_t)orow * HID + ct * 16 + lr] = dv * acc[ct][r];
        }
    }
}

// ---------------- agg1: a1[i] = relu(dinv[i]*(h1s[i] + sum_e h1s[src]) + b1) ----------------
// 8-way unrolled edge loop: 8 independent gathers in flight per wave.
__global__ __launch_bounds__(256) void k_agg1(const float* __restrict__ h1s,
                                              const int* __restrict__ rowptr,
                                              const int* __restrict__ ssort,
                                              const float* __restrict__ dinv,
                                              const float* __restrict__ b1,
                                              float* __restrict__ a1, int N) {
    int lane = threadIdx.x & 63;
    int node = blockIdx.x * 4 + (threadIdx.x >> 6);
    if (node >= N) return;
    float s0 = h1s[(size_t)node * HID + lane];   // self-loop term
    float s1 = 0.f, s2 = 0.f, s3 = 0.f, s4 = 0.f, s5 = 0.f, s6 = 0.f, s7 = 0.f;
    int e0 = rowptr[node], end = rowptr[node + 1];
    for (int e = e0; e < end; e += 8) {
        int ix[8];
        #pragma unroll
        for (int k = 0; k < 8; ++k) ix[k] = (e + k < end) ? ssort[e + k] : ssort[e];
        float v[8];
        #pragma unroll
        for (int k = 0; k < 8; ++k) v[k] = h1s[(size_t)ix[k] * HID + lane];
        s0 += v[0];
        s1 += (e + 1 < end) ? v[1] : 0.f;
        s2 += (e + 2 < end) ? v[2] : 0.f;
        s3 += (e + 3 < end) ? v[3] : 0.f;
        s4 += (e + 4 < end) ? v[4] : 0.f;
        s5 += (e + 5 < end) ? v[5] : 0.f;
        s6 += (e + 6 < end) ? v[6] : 0.f;
        s7 += (e + 7 < end) ? v[7] : 0.f;
    }
    float s = ((s0 + s1) + (s2 + s3)) + ((s4 + s5) + (s6 + s7));
    float v = dinv[node] * s + b1[lane];
    a1[(size_t)node * HID + lane] = fmaxf(v, 0.0f);
}

// ---------------- GEMM2: h2s[i][c] = dinv[i] * dot(a1[i,:64], W2[:,c]), c<40 ----------------
__global__ __launch_bounds__(256) void k_gemm2(const float* __restrict__ a1,
                                               const float* __restrict__ W2,
                                               const float* __restrict__ dinv,
                                               float* __restrict__ h2s, int N) {
    __shared__ float as[32 * 68];         // [r][k], stride 68
    __shared__ float wl[HID * OUTC];      // 2560 floats
    int t = threadIdx.x;
    int row0 = blockIdx.x * 32;

    #pragma unroll
    for (int q0 = 0; q0 < 2; ++q0) {
        int q = t + q0 * 256;             // float4 index over 512
        int r = q >> 4, kq = q & 15;
        int row = row0 + r; if (row >= N) row = N - 1;
        float4 v = *(const float4*)&a1[(size_t)row * HID + kq * 4];
        *(float4*)&as[r * 68 + kq * 4] = v;
    }
    #pragma unroll
    for (int q0 = 0; q0 < 3; ++q0) {
        int q = t + q0 * 256;             // float4 index over 640
        if (q < 640) *(float4*)&wl[q * 4] = *(const float4*)&W2[q * 4];
    }
    __syncthreads();

    int lr = t >> 3, lc0 = t & 7;
    int row = row0 + lr;
    float acc[5] = {};
    #pragma unroll
    for (int k = 0; k < HID; ++k) {
        float a = as[lr * 68 + k];
        #pragma unroll
        for (int m = 0; m < 5; ++m)
            acc[m] = fmaf(a, wl[k * OUTC + lc0 + m * 8], acc[m]);
    }
    if (row < N) {
        float dv = dinv[row];
        #pragma unroll
        for (int m = 0; m < 5; ++m)
            h2s[(size_t)row * OUTC + lc0 + m * 8] = dv * acc[m];
    }
}

// ---------------- agg2 + bias + softmax (8-way unrolled gathers) ----------------
__global__ __launch_bounds__(256) void k_agg2(const float* __restrict__ h2s,
                                              const int* __restrict__ rowptr,
                                              const int* __restrict__ ssort,
                                              const float* __restrict__ dinv,
                                              const float* __restrict__ b2,
                                              float* __restrict__ out, int N) {
    int lane = threadIdx.x & 63;
    int node = blockIdx.x * 4 + (threadIdx.x >> 6);
    if (node >= N) return;
    bool act = lane < OUTC;
    float s0 = act ? h2s[(size_t)node * OUTC + lane] : 0.0f;
    float s1 = 0.f, s2 = 0.f, s3 = 0.f, s4 = 0.f, s5 = 0.f, s6 = 0.f, s7 = 0.f;
    int e0 = rowptr[node], end = rowptr[node + 1];
    for (int e = e0; e < end; e += 8) {
        int ix[8];
        #pragma unroll
        for (int k = 0; k < 8; ++k) ix[k] = (e + k < end) ? ssort[e + k] : ssort[e];
        float v[8];
        #pragma unroll
        for (int k = 0; k < 8; ++k) v[k] = act ? h2s[(size_t)ix[k] * OUTC + lane] : 0.f;
        s0 += v[0];
        s1 += (e + 1 < end) ? v[1] : 0.f;
        s2 += (e + 2 < end) ? v[2] : 0.f;
        s3 += (e + 3 < end) ? v[3] : 0.f;
        s4 += (e + 4 < end) ? v[4] : 0.f;
        s5 += (e + 5 < end) ? v[5] : 0.f;
        s6 += (e + 6 < end) ? v[6] : 0.f;
        s7 += (e + 7 < end) ? v[7] : 0.f;
    }
    float s = ((s0 + s1) + (s2 + s3)) + ((s4 + s5) + (s6 + s7));
    float v = act ? (dinv[node] * s + b2[lane]) : -INFINITY;
    float m = v;
    #pragma unroll
    for (int o = 32; o; o >>= 1) m = fmaxf(m, __shfl_xor(m, o));
    float p = act ? expf(v - m) : 0.0f;
    float su = p;
    #pragma unroll
    for (int o = 32; o; o >>= 1) su += __shfl_xor(su, o);
    if (act) out[(size_t)node * OUTC + lane] = p / su;
}

static inline size_t alignup(size_t v) { return (v + 255) & ~(size_t)255; }

extern "C" void kernel_launch(void* const* d_in, const int* in_sizes, int n_in,
                              void* d_out, int out_size, void* d_ws, size_t ws_size,
                              hipStream_t stream) {
    const float* x  = (const float*)d_in[0];
    const int*   ei = (const int*)d_in[1];
    const float* W1 = (const float*)d_in[2];
    const float* b1 = (const float*)d_in[3];
    const float* W2 = (const float*)d_in[4];
    const float* b2 = (const float*)d_in[5];

    const int N = in_sizes[0] / IN_C;
    const int E = in_sizes[1] / 2;
    const int* src = ei;
    const int* dst = ei + E;

    char* w = (char*)d_ws;
    int* cnt    = (int*)w;   w += alignup((size_t)N * 4);
    int* rowptr = (int*)w;   w += alignup((size_t)(N + 1) * 4);
    int* bsum   = (int*)w;   w += alignup(256 * 4);
    int* bpre   = (int*)w;   w += alignup(256 * 4);
    int* fillc  = (int*)w;   w += alignup((size_t)N * 4);
    int* ssort  = (int*)w;   w += alignup((size_t)E * 4);
    float* dinv = (float*)w; w += alignup((size_t)N * 4);
    float* h1s  = (float*)w; w += alignup((size_t)N * HID * 4);
    float* a1   = (float*)w; w += alignup((size_t)N * HID * 4);
    float* h2s  = (float*)w; w += alignup((size_t)N * OUTC * 4);
    ushort* WThi = (ushort*)w; w += alignup((size_t)HID * IN_C * 2);
    ushort* WTlo = (ushort*)w; w += alignup((size_t)HID * IN_C * 2);

    hipMemsetAsync(cnt,   0, (size_t)N * 4, stream);
    hipMemsetAsync(fillc, 0, (size_t)N * 4, stream);

    const int nb = (N + 255) / 256;
    k_wsplit<<<(HID * IN_C + 255) / 256, 256, 0, stream>>>(W1, WThi, WTlo);
    k_hist <<<(E + 255) / 256, 256, 0, stream>>>(dst, E, cnt);
    k_scan1<<<nb, 256, 0, stream>>>(cnt, N, rowptr, bsum);
    k_scan2<<<1, 256, 0, stream>>>(bsum, nb, bpre);
    k_scan3<<<nb, 256, 0, stream>>>(rowptr, bpre, cnt, dinv, N, E);
    k_fill <<<(E + 255) / 256, 256, 0, stream>>>(src, dst, E, rowptr, fillc, ssort);

    k_gemm1<<<(N + 63) / 64, 256, 0, stream>>>(x, WThi, WTlo, dinv, h1s, N);
    k_agg1 <<<(N + 3) / 4, 256, 0, stream>>>(h1s, rowptr, ssort, dinv, b1, a1, N);
    k_gemm2<<<(N + 31) / 32, 256, 0, stream>>>(a1, W2, dinv, h2s, N);
    k_agg2 <<<(N + 3) / 4, 256, 0, stream>>>(h2s, rowptr, ssort, dinv, b2, (float*)d_out, N);
}

// Round 4
// 253.303 us; speedup vs baseline: 1.0281x; 1.0281x over previous
//
#include <hip/hip_runtime.h>
#include <math.h>

#define IN_C 512
#define HID  64
#define OUTC 40

typedef __attribute__((ext_vector_type(8))) short bf16x8;
typedef __attribute__((ext_vector_type(4))) float f32x4;

// ---------------- histogram of dst ----------------
__global__ void k_hist(const int* __restrict__ dst, int E, int* __restrict__ cnt) {
    int i = blockIdx.x * blockDim.x + threadIdx.x;
    if (i < E) atomicAdd(&cnt[dst[i]], 1);
}

// ---------------- prefix scan (3 kernels) ----------------
__global__ void k_scan1(const int* __restrict__ cnt, int N,
                        int* __restrict__ rowptr, int* __restrict__ bsum) {
    __shared__ int s[256];
    int t = threadIdx.x;
    int i = blockIdx.x * 256 + t;
    int v = (i < N) ? cnt[i] : 0;
    int x = v;
    s[t] = x; __syncthreads();
    #pragma unroll
    for (int o = 1; o < 256; o <<= 1) {
        int y = (t >= o) ? s[t - o] : 0;
        __syncthreads();
        x += y; s[t] = x;
        __syncthreads();
    }
    if (i < N) rowptr[i] = x - v;          // exclusive
    if (t == 255) bsum[blockIdx.x] = x;    // block total
}

__global__ void k_scan2(const int* __restrict__ bsum, int nb, int* __restrict__ bpre) {
    __shared__ int s[256];
    int t = threadIdx.x;
    int v = (t < nb) ? bsum[t] : 0;
    int x = v;
    s[t] = x; __syncthreads();
    #pragma unroll
    for (int o = 1; o < 256; o <<= 1) {
        int y = (t >= o) ? s[t - o] : 0;
        __syncthreads();
        x += y; s[t] = x;
        __syncthreads();
    }
    bpre[t] = x - v;
}

__global__ void k_scan3(int* __restrict__ rowptr, const int* __restrict__ bpre,
                        const int* __restrict__ cnt, float* __restrict__ dinv,
                        int N, int E) {
    int i = blockIdx.x * blockDim.x + threadIdx.x;
    if (i < N) {
        rowptr[i] += bpre[i >> 8];
        dinv[i] = rsqrtf(1.0f + (float)cnt[i]);   // self-loop => deg >= 1
        if (i == 0) rowptr[N] = E;
    }
}

// ---------------- counting-sort fill ----------------
__global__ void k_fill(const int* __restrict__ src, const int* __restrict__ dst, int E,
                       const int* __restrict__ rowptr, int* __restrict__ fillc,
                       int* __restrict__ ssort) {
    int i = blockIdx.x * blockDim.x + threadIdx.x;
    if (i < E) {
        int d = dst[i];
        int p = rowptr[d] + atomicAdd(&fillc[d], 1);
        ssort[p] = src[i];
    }
}

// ---------------- W1 split to hi/lo bf16, transposed: WT[c][k] ----------------
__global__ void k_wsplit(const float* __restrict__ W,
                         ushort* __restrict__ hi, ushort* __restrict__ lo) {
    int i = blockIdx.x * blockDim.x + threadIdx.x;   // over 64*512
    if (i >= HID * IN_C) return;
    int c = i >> 9, k = i & 511;
    float v = W[(size_t)k * HID + c];
    uint ub = __float_as_uint(v);
    uint hb = ub & 0xFFFF0000u;
    float lf = v - __uint_as_float(hb);
    hi[i] = (ushort)(ub >> 16);
    lo[i] = (ushort)(__float_as_uint(lf) >> 16);
}

// ---------------- GEMM1 via split-bf16 MFMA, no LDS, software-pipelined ----------------
// h1s[i][c] = dinv[i] * dot(x[i,:512], W1[:,c])
// Block: 64 rows, 4 waves; wave w: rows w*16..w*16+15, all 64 cols.
// x double-buffered at 128-k super-tile level (loads issue ~4 iters ahead);
// B double-buffered at 32-k iteration level (~1 iter ahead, L2-resident).
__global__ __launch_bounds__(256) void k_gemm1(const float* __restrict__ x,
                                               const ushort* __restrict__ WThi,
                                               const ushort* __restrict__ WTlo,
                                               const float* __restrict__ dinv,
                                               float* __restrict__ h1s, int N) {
    int t = threadIdx.x;
    int wid = t >> 6, lane = t & 63;
    int row0 = blockIdx.x * 64 + wid * 16;
    int lr = lane & 15;          // A row within tile / C col within tile
    int lko = lane >> 4;         // k-group (×8)
    int arow = row0 + lr; if (arow >= N) arow = N - 1;
    const float* xrow = x + (size_t)arow * IN_C + lko * 8;
    const ushort* bh = WThi + (size_t)lr * IN_C + lko * 8;
    const ushort* bl = WTlo + (size_t)lr * IN_C + lko * 8;

    f32x4 acc[4] = {{0,0,0,0},{0,0,0,0},{0,0,0,0},{0,0,0,0}};

    float4 xb[2][8];             // 2 super-tiles x 128 k
    bf16x8 bhb[2][4], blb[2][4]; // 2 iterations x 4 col-tiles

    // prologue: super-tile 0 of x, iteration 0 of B
    #pragma unroll
    for (int j = 0; j < 4; ++j) {
        xb[0][2 * j]     = *(const float4*)(xrow + j * 32);
        xb[0][2 * j + 1] = *(const float4*)(xrow + j * 32 + 4);
    }
    #pragma unroll
    for (int ct = 0; ct < 4; ++ct) {
        bhb[0][ct] = *(const bf16x8*)(bh + (size_t)ct * 16 * IN_C);
        blb[0][ct] = *(const bf16x8*)(bl + (size_t)ct * 16 * IN_C);
    }

    #pragma unroll
    for (int it = 0; it < 16; ++it) {
        const int s = it >> 2, i = it & 3;
        // prefetch next super-tile's x (issued 4 iterations ahead of use)
        if (i == 0 && s < 3) {
            #pragma unroll
            for (int j = 0; j < 4; ++j) {
                xb[(s + 1) & 1][2 * j]     = *(const float4*)(xrow + (s + 1) * 128 + j * 32);
                xb[(s + 1) & 1][2 * j + 1] = *(const float4*)(xrow + (s + 1) * 128 + j * 32 + 4);
            }
        }
        // prefetch next iteration's B fragments
        if (it < 15) {
            #pragma unroll
            for (int ct = 0; ct < 4; ++ct) {
                bhb[(it + 1) & 1][ct] = *(const bf16x8*)(bh + (it + 1) * 32 + (size_t)ct * 16 * IN_C);
                blb[(it + 1) & 1][ct] = *(const bf16x8*)(bl + (it + 1) * 32 + (size_t)ct * 16 * IN_C);
            }
        }
        // convert current x fragment to hi/lo bf16
        float xv[8];
        *(float4*)&xv[0] = xb[s & 1][2 * i];
        *(float4*)&xv[4] = xb[s & 1][2 * i + 1];
        bf16x8 ahi, alo;
        #pragma unroll
        for (int j = 0; j < 8; ++j) {
            uint ub = __float_as_uint(xv[j]);
            float hf = __uint_as_float(ub & 0xFFFF0000u);
            float lf = xv[j] - hf;
            ahi[j] = (short)(ub >> 16);
            alo[j] = (short)(__float_as_uint(lf) >> 16);
        }
        // 12 MFMAs (3-term split product, 4 col-tiles)
        #pragma unroll
        for (int ct = 0; ct < 4; ++ct) {
            acc[ct] = __builtin_amdgcn_mfma_f32_16x16x32_bf16(ahi, bhb[it & 1][ct], acc[ct], 0, 0, 0);
            acc[ct] = __builtin_amdgcn_mfma_f32_16x16x32_bf16(alo, bhb[it & 1][ct], acc[ct], 0, 0, 0);
            acc[ct] = __builtin_amdgcn_mfma_f32_16x16x32_bf16(ahi, blb[it & 1][ct], acc[ct], 0, 0, 0);
        }
    }

    // C/D layout (m89-verified): col = lane&15, row = (lane>>4)*4 + reg
    #pragma unroll
    for (int r = 0; r < 4; ++r) {
        int orow = row0 + lko * 4 + r;
        if (orow < N) {
            float dv = dinv[orow];
            #pragma unroll
            for (int ct = 0; ct < 4; ++ct)
                h1s[(size_t)orow * HID + ct * 16 + lr] = dv * acc[ct][r];
        }
    }
}

// ---------------- agg1: a1[i] = relu(dinv[i]*(h1s[i] + sum_e h1s[src]) + b1) ----------------
// 8-way unrolled edge loop: 8 independent gathers in flight per wave.
__global__ __launch_bounds__(256) void k_agg1(const float* __restrict__ h1s,
                                              const int* __restrict__ rowptr,
                                              const int* __restrict__ ssort,
                                              const float* __restrict__ dinv,
                                              const float* __restrict__ b1,
                                              float* __restrict__ a1, int N) {
    int lane = threadIdx.x & 63;
    int node = blockIdx.x * 4 + (threadIdx.x >> 6);
    if (node >= N) return;
    float s0 = h1s[(size_t)node * HID + lane];   // self-loop term
    float s1 = 0.f, s2 = 0.f, s3 = 0.f, s4 = 0.f, s5 = 0.f, s6 = 0.f, s7 = 0.f;
    int e0 = rowptr[node], end = rowptr[node + 1];
    for (int e = e0; e < end; e += 8) {
        int ix[8];
        #pragma unroll
        for (int k = 0; k < 8; ++k) ix[k] = (e + k < end) ? ssort[e + k] : ssort[e];
        float v[8];
        #pragma unroll
        for (int k = 0; k < 8; ++k) v[k] = h1s[(size_t)ix[k] * HID + lane];
        s0 += v[0];
        s1 += (e + 1 < end) ? v[1] : 0.f;
        s2 += (e + 2 < end) ? v[2] : 0.f;
        s3 += (e + 3 < end) ? v[3] : 0.f;
        s4 += (e + 4 < end) ? v[4] : 0.f;
        s5 += (e + 5 < end) ? v[5] : 0.f;
        s6 += (e + 6 < end) ? v[6] : 0.f;
        s7 += (e + 7 < end) ? v[7] : 0.f;
    }
    float s = ((s0 + s1) + (s2 + s3)) + ((s4 + s5) + (s6 + s7));
    float v = dinv[node] * s + b1[lane];
    a1[(size_t)node * HID + lane] = fmaxf(v, 0.0f);
}

// ---------------- GEMM2: h2s[i][c] = dinv[i] * dot(a1[i,:64], W2[:,c]), c<40 ----------------
__global__ __launch_bounds__(256) void k_gemm2(const float* __restrict__ a1,
                                               const float* __restrict__ W2,
                                               const float* __restrict__ dinv,
                                               float* __restrict__ h2s, int N) {
    __shared__ float as[32 * 68];         // [r][k], stride 68
    __shared__ float wl[HID * OUTC];      // 2560 floats
    int t = threadIdx.x;
    int row0 = blockIdx.x * 32;

    #pragma unroll
    for (int q0 = 0; q0 < 2; ++q0) {
        int q = t + q0 * 256;             // float4 index over 512
        int r = q >> 4, kq = q & 15;
        int row = row0 + r; if (row >= N) row = N - 1;
        float4 v = *(const float4*)&a1[(size_t)row * HID + kq * 4];
        *(float4*)&as[r * 68 + kq * 4] = v;
    }
    #pragma unroll
    for (int q0 = 0; q0 < 3; ++q0) {
        int q = t + q0 * 256;             // float4 index over 640
        if (q < 640) *(float4*)&wl[q * 4] = *(const float4*)&W2[q * 4];
    }
    __syncthreads();

    int lr = t >> 3, lc0 = t & 7;
    int row = row0 + lr;
    float acc[5] = {};
    #pragma unroll
    for (int k = 0; k < HID; ++k) {
        float a = as[lr * 68 + k];
        #pragma unroll
        for (int m = 0; m < 5; ++m)
            acc[m] = fmaf(a, wl[k * OUTC + lc0 + m * 8], acc[m]);
    }
    if (row < N) {
        float dv = dinv[row];
        #pragma unroll
        for (int m = 0; m < 5; ++m)
            h2s[(size_t)row * OUTC + lc0 + m * 8] = dv * acc[m];
    }
}

// ---------------- agg2 + bias + softmax (8-way unrolled gathers) ----------------
__global__ __launch_bounds__(256) void k_agg2(const float* __restrict__ h2s,
                                              const int* __restrict__ rowptr,
                                              const int* __restrict__ ssort,
                                              const float* __restrict__ dinv,
                                              const float* __restrict__ b2,
                                              float* __restrict__ out, int N) {
    int lane = threadIdx.x & 63;
    int node = blockIdx.x * 4 + (threadIdx.x >> 6);
    if (node >= N) return;
    bool act = lane < OUTC;
    float s0 = act ? h2s[(size_t)node * OUTC + lane] : 0.0f;
    float s1 = 0.f, s2 = 0.f, s3 = 0.f, s4 = 0.f, s5 = 0.f, s6 = 0.f, s7 = 0.f;
    int e0 = rowptr[node], end = rowptr[node + 1];
    for (int e = e0; e < end; e += 8) {
        int ix[8];
        #pragma unroll
        for (int k = 0; k < 8; ++k) ix[k] = (e + k < end) ? ssort[e + k] : ssort[e];
        float v[8];
        #pragma unroll
        for (int k = 0; k < 8; ++k) v[k] = act ? h2s[(size_t)ix[k] * OUTC + lane] : 0.f;
        s0 += v[0];
        s1 += (e + 1 < end) ? v[1] : 0.f;
        s2 += (e + 2 < end) ? v[2] : 0.f;
        s3 += (e + 3 < end) ? v[3] : 0.f;
        s4 += (e + 4 < end) ? v[4] : 0.f;
        s5 += (e + 5 < end) ? v[5] : 0.f;
        s6 += (e + 6 < end) ? v[6] : 0.f;
        s7 += (e + 7 < end) ? v[7] : 0.f;
    }
    float s = ((s0 + s1) + (s2 + s3)) + ((s4 + s5) + (s6 + s7));
    float v = act ? (dinv[node] * s + b2[lane]) : -INFINITY;
    float m = v;
    #pragma unroll
    for (int o = 32; o; o >>= 1) m = fmaxf(m, __shfl_xor(m, o));
    float p = act ? expf(v - m) : 0.0f;
    float su = p;
    #pragma unroll
    for (int o = 32; o; o >>= 1) su += __shfl_xor(su, o);
    if (act) out[(size_t)node * OUTC + lane] = p / su;
}

static inline size_t alignup(size_t v) { return (v + 255) & ~(size_t)255; }

extern "C" void kernel_launch(void* const* d_in, const int* in_sizes, int n_in,
                              void* d_out, int out_size, void* d_ws, size_t ws_size,
                              hipStream_t stream) {
    const float* x  = (const float*)d_in[0];
    const int*   ei = (const int*)d_in[1];
    const float* W1 = (const float*)d_in[2];
    const float* b1 = (const float*)d_in[3];
    const float* W2 = (const float*)d_in[4];
    const float* b2 = (const float*)d_in[5];

    const int N = in_sizes[0] / IN_C;
    const int E = in_sizes[1] / 2;
    const int* src = ei;
    const int* dst = ei + E;

    char* w = (char*)d_ws;
    int* cnt    = (int*)w;   w += alignup((size_t)N * 4);
    int* rowptr = (int*)w;   w += alignup((size_t)(N + 1) * 4);
    int* bsum   = (int*)w;   w += alignup(256 * 4);
    int* bpre   = (int*)w;   w += alignup(256 * 4);
    int* fillc  = (int*)w;   w += alignup((size_t)N * 4);
    int* ssort  = (int*)w;   w += alignup((size_t)E * 4);
    float* dinv = (float*)w; w += alignup((size_t)N * 4);
    float* h1s  = (float*)w; w += alignup((size_t)N * HID * 4);
    float* a1   = (float*)w; w += alignup((size_t)N * HID * 4);
    float* h2s  = (float*)w; w += alignup((size_t)N * OUTC * 4);
    ushort* WThi = (ushort*)w; w += alignup((size_t)HID * IN_C * 2);
    ushort* WTlo = (ushort*)w; w += alignup((size_t)HID * IN_C * 2);

    hipMemsetAsync(cnt,   0, (size_t)N * 4, stream);
    hipMemsetAsync(fillc, 0, (size_t)N * 4, stream);

    const int nb = (N + 255) / 256;
    k_wsplit<<<(HID * IN_C + 255) / 256, 256, 0, stream>>>(W1, WThi, WTlo);
    k_hist <<<(E + 255) / 256, 256, 0, stream>>>(dst, E, cnt);
    k_scan1<<<nb, 256, 0, stream>>>(cnt, N, rowptr, bsum);
    k_scan2<<<1, 256, 0, stream>>>(bsum, nb, bpre);
    k_scan3<<<nb, 256, 0, stream>>>(rowptr, bpre, cnt, dinv, N, E);
    k_fill <<<(E + 255) / 256, 256, 0, stream>>>(src, dst, E, rowptr, fillc, ssort);

    k_gemm1<<<(N + 63) / 64, 256, 0, stream>>>(x, WThi, WTlo, dinv, h1s, N);
    k_agg1 <<<(N + 3) / 4, 256, 0, stream>>>(h1s, rowptr, ssort, dinv, b1, a1, N);
    k_gemm2<<<(N + 31) / 32, 256, 0, stream>>>(a1, W2, dinv, h2s, N);
    k_agg2 <<<(N + 3) / 4, 256, 0, stream>>>(h2s, rowptr, ssort, dinv, b2, (float*)d_out, N);
}

// Round 5
// 205.160 us; speedup vs baseline: 1.2693x; 1.2347x over previous
//
#include <hip/hip_runtime.h>
#include <math.h>

#define IN_C 512
#define HID  64
#define OUTC 40

typedef __attribute__((ext_vector_type(8))) short bf16x8;
typedef __attribute__((ext_vector_type(4))) short bf16x4;
typedef __attribute__((ext_vector_type(4))) float f32x4;

// ---------------- histogram of dst ----------------
__global__ void k_hist(const int* __restrict__ dst, int E, int* __restrict__ cnt) {
    int i = blockIdx.x * blockDim.x + threadIdx.x;
    if (i < E) atomicAdd(&cnt[dst[i]], 1);
}

// ---------------- prefix scan (3 kernels) ----------------
__global__ void k_scan1(const int* __restrict__ cnt, int N,
                        int* __restrict__ rowptr, int* __restrict__ bsum) {
    __shared__ int s[256];
    int t = threadIdx.x;
    int i = blockIdx.x * 256 + t;
    int v = (i < N) ? cnt[i] : 0;
    int x = v;
    s[t] = x; __syncthreads();
    #pragma unroll
    for (int o = 1; o < 256; o <<= 1) {
        int y = (t >= o) ? s[t - o] : 0;
        __syncthreads();
        x += y; s[t] = x;
        __syncthreads();
    }
    if (i < N) rowptr[i] = x - v;          // exclusive
    if (t == 255) bsum[blockIdx.x] = x;    // block total
}

__global__ void k_scan2(const int* __restrict__ bsum, int nb, int* __restrict__ bpre) {
    __shared__ int s[256];
    int t = threadIdx.x;
    int v = (t < nb) ? bsum[t] : 0;
    int x = v;
    s[t] = x; __syncthreads();
    #pragma unroll
    for (int o = 1; o < 256; o <<= 1) {
        int y = (t >= o) ? s[t - o] : 0;
        __syncthreads();
        x += y; s[t] = x;
        __syncthreads();
    }
    bpre[t] = x - v;
}

__global__ void k_scan3(int* __restrict__ rowptr, const int* __restrict__ bpre,
                        const int* __restrict__ cnt, float* __restrict__ dinv,
                        int N, int E) {
    int i = blockIdx.x * blockDim.x + threadIdx.x;
    if (i < N) {
        rowptr[i] += bpre[i >> 8];
        dinv[i] = rsqrtf(1.0f + (float)cnt[i]);   // self-loop => deg >= 1
        if (i == 0) rowptr[N] = E;
    }
}

// ---------------- counting-sort fill ----------------
__global__ void k_fill(const int* __restrict__ src, const int* __restrict__ dst, int E,
                       const int* __restrict__ rowptr, int* __restrict__ fillc,
                       int* __restrict__ ssort) {
    int i = blockIdx.x * blockDim.x + threadIdx.x;
    if (i < E) {
        int d = dst[i];
        int p = rowptr[d] + atomicAdd(&fillc[d], 1);
        ssort[p] = src[i];
    }
}

// ---------------- W1 split to hi/lo bf16, transposed: WT[c][k] ----------------
__global__ void k_wsplit(const float* __restrict__ W,
                         ushort* __restrict__ hi, ushort* __restrict__ lo) {
    int i = blockIdx.x * blockDim.x + threadIdx.x;   // over 64*512
    if (i >= HID * IN_C) return;
    int c = i >> 9, k = i & 511;
    float v = W[(size_t)k * HID + c];
    uint ub = __float_as_uint(v);
    uint hb = ub & 0xFFFF0000u;
    float lf = v - __uint_as_float(hb);
    hi[i] = (ushort)(ub >> 16);
    lo[i] = (ushort)(__float_as_uint(lf) >> 16);
}

// ---------------- GEMM1: LDS-staged split-bf16 MFMA ----------------
// h1s[i][c] = dinv[i] * dot(x[i,:512], W1[:,c])
// BM=64 rows x BN=64 cols, BK=32, 4 waves (2M x 2N), double-buffered LDS.
// LDS row stride = 40 bf16 (80 B): 16-lane b128 frag reads walk all 8
// 16B slots of the 32-bank window -> <=2-way aliasing (free).
__global__ __launch_bounds__(256) void k_gemm1(const float* __restrict__ x,
                                               const ushort* __restrict__ WThi,
                                               const ushort* __restrict__ WTlo,
                                               const float* __restrict__ dinv,
                                               float* __restrict__ h1s, int N) {
    __shared__ ushort Ah[2][64 * 40], Al[2][64 * 40];
    __shared__ ushort Bh[2][64 * 40], Bl[2][64 * 40];
    int t = threadIdx.x;
    int wid = t >> 6, lane = t & 63;
    int lr = lane & 15, lko = lane >> 4;
    int wm = wid >> 1, wn = wid & 1;
    int row0 = blockIdx.x * 64;

    // staging geometry
    int srow = t >> 3, sf4 = t & 7;       // x: rows srow, srow+32; 16B chunk sf4
    int scol = t >> 2, sseg = t & 3;      // B: col scol, 16B chunk sseg
    int xr0 = row0 + srow;      if (xr0 >= N) xr0 = N - 1;
    int xr1 = row0 + srow + 32; if (xr1 >= N) xr1 = N - 1;
    const float* xp0 = x + (size_t)xr0 * IN_C + sf4 * 4;
    const float* xp1 = x + (size_t)xr1 * IN_C + sf4 * 4;
    const ushort* bhp = WThi + (size_t)scol * IN_C + sseg * 8;
    const ushort* blp = WTlo + (size_t)scol * IN_C + sseg * 8;

    f32x4 acc[2][2] = {};
    float4 xrg[2];
    bf16x8 bhr, blr;

    auto stage_load = [&](int kt) {
        xrg[0] = *(const float4*)(xp0 + kt);
        xrg[1] = *(const float4*)(xp1 + kt);
        bhr = *(const bf16x8*)(bhp + kt);
        blr = *(const bf16x8*)(blp + kt);
    };
    auto stage_write = [&](int b) {
        #pragma unroll
        for (int p = 0; p < 2; ++p) {
            float xv[4];
            *(float4*)xv = xrg[p];
            bf16x4 h, l;
            #pragma unroll
            for (int j = 0; j < 4; ++j) {
                uint ub = __float_as_uint(xv[j]);
                float hf = __uint_as_float(ub & 0xFFFF0000u);
                float lf = xv[j] - hf;
                h[j] = (short)(ub >> 16);
                l[j] = (short)(__float_as_uint(lf) >> 16);
            }
            int row = srow + p * 32;
            *(bf16x4*)&Ah[b][row * 40 + sf4 * 4] = h;
            *(bf16x4*)&Al[b][row * 40 + sf4 * 4] = l;
        }
        *(bf16x8*)&Bh[b][scol * 40 + sseg * 8] = bhr;
        *(bf16x8*)&Bl[b][scol * 40 + sseg * 8] = blr;
    };
    auto compute = [&](int b) {
        bf16x8 afh[2], afl[2], bfh[2], bfl[2];
        #pragma unroll
        for (int mf = 0; mf < 2; ++mf) {
            int row = wm * 32 + mf * 16 + lr;
            afh[mf] = *(const bf16x8*)&Ah[b][row * 40 + lko * 8];
            afl[mf] = *(const bf16x8*)&Al[b][row * 40 + lko * 8];
        }
        #pragma unroll
        for (int nf = 0; nf < 2; ++nf) {
            int col = wn * 32 + nf * 16 + lr;
            bfh[nf] = *(const bf16x8*)&Bh[b][col * 40 + lko * 8];
            bfl[nf] = *(const bf16x8*)&Bl[b][col * 40 + lko * 8];
        }
        #pragma unroll
        for (int mf = 0; mf < 2; ++mf)
            #pragma unroll
            for (int nf = 0; nf < 2; ++nf) {
                acc[mf][nf] = __builtin_amdgcn_mfma_f32_16x16x32_bf16(afh[mf], bfh[nf], acc[mf][nf], 0, 0, 0);
                acc[mf][nf] = __builtin_amdgcn_mfma_f32_16x16x32_bf16(afl[mf], bfh[nf], acc[mf][nf], 0, 0, 0);
                acc[mf][nf] = __builtin_amdgcn_mfma_f32_16x16x32_bf16(afh[mf], bfl[nf], acc[mf][nf], 0, 0, 0);
            }
    };

    stage_load(0);
    stage_write(0);
    __syncthreads();

    #pragma unroll
    for (int i = 0; i < 16; ++i) {
        if (i < 15) stage_load((i + 1) * 32);   // issue early (hidden under MFMA)
        compute(i & 1);
        if (i < 15) stage_write((i + 1) & 1);   // write late (other buffer)
        __syncthreads();
    }

    // C/D layout (m89-verified): col = lane&15, row = (lane>>4)*4 + reg
    #pragma unroll
    for (int mf = 0; mf < 2; ++mf)
        #pragma unroll
        for (int r = 0; r < 4; ++r) {
            int orow = row0 + wm * 32 + mf * 16 + lko * 4 + r;
            if (orow < N) {
                float dv = dinv[orow];
                #pragma unroll
                for (int nf = 0; nf < 2; ++nf)
                    h1s[(size_t)orow * HID + wn * 32 + nf * 16 + lr] = dv * acc[mf][nf][r];
            }
        }
}

// ---------------- agg1: a1[i] = relu(dinv[i]*(h1s[i] + sum_e h1s[src]) + b1) ----------------
// 8-way unrolled edge loop: 8 independent gathers in flight per wave.
__global__ __launch_bounds__(256) void k_agg1(const float* __restrict__ h1s,
                                              const int* __restrict__ rowptr,
                                              const int* __restrict__ ssort,
                                              const float* __restrict__ dinv,
                                              const float* __restrict__ b1,
                                              float* __restrict__ a1, int N) {
    int lane = threadIdx.x & 63;
    int node = blockIdx.x * 4 + (threadIdx.x >> 6);
    if (node >= N) return;
    float s0 = h1s[(size_t)node * HID + lane];   // self-loop term
    float s1 = 0.f, s2 = 0.f, s3 = 0.f, s4 = 0.f, s5 = 0.f, s6 = 0.f, s7 = 0.f;
    int e0 = rowptr[node], end = rowptr[node + 1];
    for (int e = e0; e < end; e += 8) {
        int ix[8];
        #pragma unroll
        for (int k = 0; k < 8; ++k) ix[k] = (e + k < end) ? ssort[e + k] : ssort[e];
        float v[8];
        #pragma unroll
        for (int k = 0; k < 8; ++k) v[k] = h1s[(size_t)ix[k] * HID + lane];
        s0 += v[0];
        s1 += (e + 1 < end) ? v[1] : 0.f;
        s2 += (e + 2 < end) ? v[2] : 0.f;
        s3 += (e + 3 < end) ? v[3] : 0.f;
        s4 += (e + 4 < end) ? v[4] : 0.f;
        s5 += (e + 5 < end) ? v[5] : 0.f;
        s6 += (e + 6 < end) ? v[6] : 0.f;
        s7 += (e + 7 < end) ? v[7] : 0.f;
    }
    float s = ((s0 + s1) + (s2 + s3)) + ((s4 + s5) + (s6 + s7));
    float v = dinv[node] * s + b1[lane];
    a1[(size_t)node * HID + lane] = fmaxf(v, 0.0f);
}

// ---------------- GEMM2: h2s[i][c] = dinv[i] * dot(a1[i,:64], W2[:,c]), c<40 ----------------
__global__ __launch_bounds__(256) void k_gemm2(const float* __restrict__ a1,
                                               const float* __restrict__ W2,
                                               const float* __restrict__ dinv,
                                               float* __restrict__ h2s, int N) {
    __shared__ float as[32 * 68];         // [r][k], stride 68
    __shared__ float wl[HID * OUTC];      // 2560 floats
    int t = threadIdx.x;
    int row0 = blockIdx.x * 32;

    #pragma unroll
    for (int q0 = 0; q0 < 2; ++q0) {
        int q = t + q0 * 256;             // float4 index over 512
        int r = q >> 4, kq = q & 15;
        int row = row0 + r; if (row >= N) row = N - 1;
        float4 v = *(const float4*)&a1[(size_t)row * HID + kq * 4];
        *(float4*)&as[r * 68 + kq * 4] = v;
    }
    #pragma unroll
    for (int q0 = 0; q0 < 3; ++q0) {
        int q = t + q0 * 256;             // float4 index over 640
        if (q < 640) *(float4*)&wl[q * 4] = *(const float4*)&W2[q * 4];
    }
    __syncthreads();

    int lr = t >> 3, lc0 = t & 7;
    int row = row0 + lr;
    float acc[5] = {};
    #pragma unroll
    for (int k = 0; k < HID; ++k) {
        float a = as[lr * 68 + k];
        #pragma unroll
        for (int m = 0; m < 5; ++m)
            acc[m] = fmaf(a, wl[k * OUTC + lc0 + m * 8], acc[m]);
    }
    if (row < N) {
        float dv = dinv[row];
        #pragma unroll
        for (int m = 0; m < 5; ++m)
            h2s[(size_t)row * OUTC + lc0 + m * 8] = dv * acc[m];
    }
}

// ---------------- agg2 + bias + softmax (8-way unrolled gathers) ----------------
__global__ __launch_bounds__(256) void k_agg2(const float* __restrict__ h2s,
                                              const int* __restrict__ rowptr,
                                              const int* __restrict__ ssort,
                                              const float* __restrict__ dinv,
                                              const float* __restrict__ b2,
                                              float* __restrict__ out, int N) {
    int lane = threadIdx.x & 63;
    int node = blockIdx.x * 4 + (threadIdx.x >> 6);
    if (node >= N) return;
    bool act = lane < OUTC;
    float s0 = act ? h2s[(size_t)node * OUTC + lane] : 0.0f;
    float s1 = 0.f, s2 = 0.f, s3 = 0.f, s4 = 0.f, s5 = 0.f, s6 = 0.f, s7 = 0.f;
    int e0 = rowptr[node], end = rowptr[node + 1];
    for (int e = e0; e < end; e += 8) {
        int ix[8];
        #pragma unroll
        for (int k = 0; k < 8; ++k) ix[k] = (e + k < end) ? ssort[e + k] : ssort[e];
        float v[8];
        #pragma unroll
        for (int k = 0; k < 8; ++k) v[k] = act ? h2s[(size_t)ix[k] * OUTC + lane] : 0.f;
        s0 += v[0];
        s1 += (e + 1 < end) ? v[1] : 0.f;
        s2 += (e + 2 < end) ? v[2] : 0.f;
        s3 += (e + 3 < end) ? v[3] : 0.f;
        s4 += (e + 4 < end) ? v[4] : 0.f;
        s5 += (e + 5 < end) ? v[5] : 0.f;
        s6 += (e + 6 < end) ? v[6] : 0.f;
        s7 += (e + 7 < end) ? v[7] : 0.f;
    }
    float s = ((s0 + s1) + (s2 + s3)) + ((s4 + s5) + (s6 + s7));
    float v = act ? (dinv[node] * s + b2[lane]) : -INFINITY;
    float m = v;
    #pragma unroll
    for (int o = 32; o; o >>= 1) m = fmaxf(m, __shfl_xor(m, o));
    float p = act ? expf(v - m) : 0.0f;
    float su = p;
    #pragma unroll
    for (int o = 32; o; o >>= 1) su += __shfl_xor(su, o);
    if (act) out[(size_t)node * OUTC + lane] = p / su;
}

static inline size_t alignup(size_t v) { return (v + 255) & ~(size_t)255; }

extern "C" void kernel_launch(void* const* d_in, const int* in_sizes, int n_in,
                              void* d_out, int out_size, void* d_ws, size_t ws_size,
                              hipStream_t stream) {
    const float* x  = (const float*)d_in[0];
    const int*   ei = (const int*)d_in[1];
    const float* W1 = (const float*)d_in[2];
    const float* b1 = (const float*)d_in[3];
    const float* W2 = (const float*)d_in[4];
    const float* b2 = (const float*)d_in[5];

    const int N = in_sizes[0] / IN_C;
    const int E = in_sizes[1] / 2;
    const int* src = ei;
    const int* dst = ei + E;

    char* w = (char*)d_ws;
    int* cnt    = (int*)w;   w += alignup((size_t)N * 4);
    int* rowptr = (int*)w;   w += alignup((size_t)(N + 1) * 4);
    int* bsum   = (int*)w;   w += alignup(256 * 4);
    int* bpre   = (int*)w;   w += alignup(256 * 4);
    int* fillc  = (int*)w;   w += alignup((size_t)N * 4);
    int* ssort  = (int*)w;   w += alignup((size_t)E * 4);
    float* dinv = (float*)w; w += alignup((size_t)N * 4);
    float* h1s  = (float*)w; w += alignup((size_t)N * HID * 4);
    float* a1   = (float*)w; w += alignup((size_t)N * HID * 4);
    float* h2s  = (float*)w; w += alignup((size_t)N * OUTC * 4);
    ushort* WThi = (ushort*)w; w += alignup((size_t)HID * IN_C * 2);
    ushort* WTlo = (ushort*)w; w += alignup((size_t)HID * IN_C * 2);

    hipMemsetAsync(cnt,   0, (size_t)N * 4, stream);
    hipMemsetAsync(fillc, 0, (size_t)N * 4, stream);

    const int nb = (N + 255) / 256;
    k_wsplit<<<(HID * IN_C + 255) / 256, 256, 0, stream>>>(W1, WThi, WTlo);
    k_hist <<<(E + 255) / 256, 256, 0, stream>>>(dst, E, cnt);
    k_scan1<<<nb, 256, 0, stream>>>(cnt, N, rowptr, bsum);
    k_scan2<<<1, 256, 0, stream>>>(bsum, nb, bpre);
    k_scan3<<<nb, 256, 0, stream>>>(rowptr, bpre, cnt, dinv, N, E);
    k_fill <<<(E + 255) / 256, 256, 0, stream>>>(src, dst, E, rowptr, fillc, ssort);

    k_gemm1<<<(N + 63) / 64, 256, 0, stream>>>(x, WThi, WTlo, dinv, h1s, N);
    k_agg1 <<<(N + 3) / 4, 256, 0, stream>>>(h1s, rowptr, ssort, dinv, b1, a1, N);
    k_gemm2<<<(N + 31) / 32, 256, 0, stream>>>(a1, W2, dinv, h2s, N);
    k_agg2 <<<(N + 3) / 4, 256, 0, stream>>>(h2s, rowptr, ssort, dinv, b2, (float*)d_out, N);
}

// Round 6
// 182.208 us; speedup vs baseline: 1.4292x; 1.1260x over previous
//
#include <hip/hip_runtime.h>
#include <math.h>

#define IN_C 512
#define HID  64
#define OUTC 40

typedef __attribute__((ext_vector_type(8))) short bf16x8;
typedef __attribute__((ext_vector_type(4))) short bf16x4;
typedef __attribute__((ext_vector_type(4))) float f32x4;

#define GDEPTH 12

// ---------------- histogram of dst (+ W1 split folded in as extra blocks) ----------------
__global__ void k_histsplit(const int* __restrict__ dst, int E, int* __restrict__ cnt,
                            int nbE,
                            const float* __restrict__ W,
                            ushort* __restrict__ hi, ushort* __restrict__ lo) {
    if (blockIdx.x < (unsigned)nbE) {
        int i = blockIdx.x * blockDim.x + threadIdx.x;
        if (i < E) atomicAdd(&cnt[dst[i]], 1);
    } else {
        // W1 split to hi/lo bf16, transposed: WT[c][k]
        int i = (blockIdx.x - nbE) * blockDim.x + threadIdx.x;   // over 64*512
        if (i >= HID * IN_C) return;
        int c = i >> 9, k = i & 511;
        float v = W[(size_t)k * HID + c];
        uint ub = __float_as_uint(v);
        uint hb = ub & 0xFFFF0000u;
        float lf = v - __uint_as_float(hb);
        hi[i] = (ushort)(ub >> 16);
        lo[i] = (ushort)(__float_as_uint(lf) >> 16);
    }
}

// ---------------- prefix scan (3 kernels) ----------------
__global__ void k_scan1(const int* __restrict__ cnt, int N,
                        int* __restrict__ rowptr, int* __restrict__ bsum) {
    __shared__ int s[256];
    int t = threadIdx.x;
    int i = blockIdx.x * 256 + t;
    int v = (i < N) ? cnt[i] : 0;
    int x = v;
    s[t] = x; __syncthreads();
    #pragma unroll
    for (int o = 1; o < 256; o <<= 1) {
        int y = (t >= o) ? s[t - o] : 0;
        __syncthreads();
        x += y; s[t] = x;
        __syncthreads();
    }
    if (i < N) rowptr[i] = x - v;          // exclusive
    if (t == 255) bsum[blockIdx.x] = x;    // block total
}

__global__ void k_scan2(const int* __restrict__ bsum, int nb, int* __restrict__ bpre) {
    __shared__ int s[256];
    int t = threadIdx.x;
    int v = (t < nb) ? bsum[t] : 0;
    int x = v;
    s[t] = x; __syncthreads();
    #pragma unroll
    for (int o = 1; o < 256; o <<= 1) {
        int y = (t >= o) ? s[t - o] : 0;
        __syncthreads();
        x += y; s[t] = x;
        __syncthreads();
    }
    bpre[t] = x - v;
}

__global__ void k_scan3(int* __restrict__ rowptr, const int* __restrict__ bpre,
                        const int* __restrict__ cnt, float* __restrict__ dinv,
                        int N, int E) {
    int i = blockIdx.x * blockDim.x + threadIdx.x;
    if (i < N) {
        rowptr[i] += bpre[i >> 8];
        dinv[i] = rsqrtf(1.0f + (float)cnt[i]);   // self-loop => deg >= 1
        if (i == 0) rowptr[N] = E;
    }
}

// ---------------- counting-sort fill ----------------
__global__ void k_fill(const int* __restrict__ src, const int* __restrict__ dst, int E,
                       const int* __restrict__ rowptr, int* __restrict__ fillc,
                       int* __restrict__ ssort) {
    int i = blockIdx.x * blockDim.x + threadIdx.x;
    if (i < E) {
        int d = dst[i];
        int p = rowptr[d] + atomicAdd(&fillc[d], 1);
        ssort[p] = src[i];
    }
}

// ---------------- GEMM1: LDS-staged split-bf16 MFMA ----------------
__global__ __launch_bounds__(256) void k_gemm1(const float* __restrict__ x,
                                               const ushort* __restrict__ WThi,
                                               const ushort* __restrict__ WTlo,
                                               const float* __restrict__ dinv,
                                               float* __restrict__ h1s, int N) {
    __shared__ ushort Ah[2][64 * 40], Al[2][64 * 40];
    __shared__ ushort Bh[2][64 * 40], Bl[2][64 * 40];
    int t = threadIdx.x;
    int wid = t >> 6, lane = t & 63;
    int lr = lane & 15, lko = lane >> 4;
    int wm = wid >> 1, wn = wid & 1;
    int row0 = blockIdx.x * 64;

    int srow = t >> 3, sf4 = t & 7;
    int scol = t >> 2, sseg = t & 3;
    int xr0 = row0 + srow;      if (xr0 >= N) xr0 = N - 1;
    int xr1 = row0 + srow + 32; if (xr1 >= N) xr1 = N - 1;
    const float* xp0 = x + (size_t)xr0 * IN_C + sf4 * 4;
    const float* xp1 = x + (size_t)xr1 * IN_C + sf4 * 4;
    const ushort* bhp = WThi + (size_t)scol * IN_C + sseg * 8;
    const ushort* blp = WTlo + (size_t)scol * IN_C + sseg * 8;

    f32x4 acc[2][2] = {};
    float4 xrg[2];
    bf16x8 bhr, blr;

    auto stage_load = [&](int kt) {
        xrg[0] = *(const float4*)(xp0 + kt);
        xrg[1] = *(const float4*)(xp1 + kt);
        bhr = *(const bf16x8*)(bhp + kt);
        blr = *(const bf16x8*)(blp + kt);
    };
    auto stage_write = [&](int b) {
        #pragma unroll
        for (int p = 0; p < 2; ++p) {
            float xv[4];
            *(float4*)xv = xrg[p];
            bf16x4 h, l;
            #pragma unroll
            for (int j = 0; j < 4; ++j) {
                uint ub = __float_as_uint(xv[j]);
                float hf = __uint_as_float(ub & 0xFFFF0000u);
                float lf = xv[j] - hf;
                h[j] = (short)(ub >> 16);
                l[j] = (short)(__float_as_uint(lf) >> 16);
            }
            int row = srow + p * 32;
            *(bf16x4*)&Ah[b][row * 40 + sf4 * 4] = h;
            *(bf16x4*)&Al[b][row * 40 + sf4 * 4] = l;
        }
        *(bf16x8*)&Bh[b][scol * 40 + sseg * 8] = bhr;
        *(bf16x8*)&Bl[b][scol * 40 + sseg * 8] = blr;
    };
    auto compute = [&](int b) {
        bf16x8 afh[2], afl[2], bfh[2], bfl[2];
        #pragma unroll
        for (int mf = 0; mf < 2; ++mf) {
            int row = wm * 32 + mf * 16 + lr;
            afh[mf] = *(const bf16x8*)&Ah[b][row * 40 + lko * 8];
            afl[mf] = *(const bf16x8*)&Al[b][row * 40 + lko * 8];
        }
        #pragma unroll
        for (int nf = 0; nf < 2; ++nf) {
            int col = wn * 32 + nf * 16 + lr;
            bfh[nf] = *(const bf16x8*)&Bh[b][col * 40 + lko * 8];
            bfl[nf] = *(const bf16x8*)&Bl[b][col * 40 + lko * 8];
        }
        #pragma unroll
        for (int mf = 0; mf < 2; ++mf)
            #pragma unroll
            for (int nf = 0; nf < 2; ++nf) {
                acc[mf][nf] = __builtin_amdgcn_mfma_f32_16x16x32_bf16(afh[mf], bfh[nf], acc[mf][nf], 0, 0, 0);
                acc[mf][nf] = __builtin_amdgcn_mfma_f32_16x16x32_bf16(afl[mf], bfh[nf], acc[mf][nf], 0, 0, 0);
                acc[mf][nf] = __builtin_amdgcn_mfma_f32_16x16x32_bf16(afh[mf], bfl[nf], acc[mf][nf], 0, 0, 0);
            }
    };

    stage_load(0);
    stage_write(0);
    __syncthreads();

    #pragma unroll
    for (int i = 0; i < 16; ++i) {
        if (i < 15) stage_load((i + 1) * 32);
        compute(i & 1);
        if (i < 15) stage_write((i + 1) & 1);
        __syncthreads();
    }

    #pragma unroll
    for (int mf = 0; mf < 2; ++mf)
        #pragma unroll
        for (int r = 0; r < 4; ++r) {
            int orow = row0 + wm * 32 + mf * 16 + lko * 4 + r;
            if (orow < N) {
                float dv = dinv[orow];
                #pragma unroll
                for (int nf = 0; nf < 2; ++nf)
                    h1s[(size_t)orow * HID + wn * 32 + nf * 16 + lr] = dv * acc[mf][nf][r];
            }
        }
}

// ---------------- fused agg1 + gemm2 ----------------
// per node n (one wave): a1[k] = relu(dinv*(h1s[n][k] + sum_e h1s[src][k]) + b1[k])
// then h2s[n][c] = dinv * sum_k a1[k] * W2[k][c]  (readlane broadcast + W2 in LDS)
__global__ __launch_bounds__(256) void k_agg1g2(const float* __restrict__ h1s,
                                                const int* __restrict__ rowptr,
                                                const int* __restrict__ ssort,
                                                const float* __restrict__ dinv,
                                                const float* __restrict__ b1,
                                                const float* __restrict__ W2,
                                                float* __restrict__ h2s, int N) {
    __shared__ float wl[HID * OUTC];      // 2560 floats = 10.24 KB
    int t = threadIdx.x;
    #pragma unroll
    for (int q0 = 0; q0 < 3; ++q0) {
        int q = t + q0 * 256;
        if (q < 640) *(float4*)&wl[q * 4] = *(const float4*)&W2[q * 4];
    }
    __syncthreads();

    int lane = t & 63;
    int wq = t >> 6;
    int lc = lane < OUTC ? lane : 0;
    float bias = b1[lane];
    int nq = (N + 3) >> 2;

    for (int q = blockIdx.x; q < nq; q += gridDim.x) {
        int node = q * 4 + wq;
        if (node >= N) continue;
        float s0 = h1s[(size_t)node * HID + lane];   // self-loop term
        float sv[GDEPTH];
        #pragma unroll
        for (int k = 0; k < GDEPTH; ++k) sv[k] = 0.f;
        int eu = __builtin_amdgcn_readfirstlane(rowptr[node]);
        int endu = __builtin_amdgcn_readfirstlane(rowptr[node + 1]);
        for (int e = eu; e < endu; e += GDEPTH) {
            int raw[GDEPTH];
            #pragma unroll
            for (int k = 0; k < GDEPTH; ++k) raw[k] = ssort[e + k];  // scalar s_load path
            #pragma unroll
            for (int k = 0; k < GDEPTH; ++k) {
                int ix = (e + k < endu) ? raw[k] : raw[0];
                float v = h1s[(size_t)ix * HID + lane];
                sv[k] += (e + k < endu) ? v : 0.f;
            }
        }
        float s = s0;
        #pragma unroll
        for (int k = 0; k < GDEPTH; ++k) s += sv[k];
        float dv = dinv[node];
        float a = fmaxf(fmaf(dv, s, bias), 0.0f);
        // in-wave gemm2: h2[c] = sum_k a[k] * W2[k][c]
        float acc = 0.f;
        #pragma unroll
        for (int k = 0; k < HID; ++k) {
            float ak = __uint_as_float(__builtin_amdgcn_readlane(__float_as_uint(a), k));
            acc = fmaf(ak, wl[k * OUTC + lc], acc);
        }
        if (lane < OUTC) h2s[(size_t)node * OUTC + lane] = dv * acc;
    }
}

// ---------------- agg2 + bias + softmax ----------------
__global__ __launch_bounds__(256) void k_agg2(const float* __restrict__ h2s,
                                              const int* __restrict__ rowptr,
                                              const int* __restrict__ ssort,
                                              const float* __restrict__ dinv,
                                              const float* __restrict__ b2,
                                              float* __restrict__ out, int N) {
    int lane = threadIdx.x & 63;
    int node = blockIdx.x * 4 + (threadIdx.x >> 6);
    if (node >= N) return;
    bool act = lane < OUTC;
    int lc = act ? lane : 0;
    float s0 = h2s[(size_t)node * OUTC + lc];
    float sv[GDEPTH];
    #pragma unroll
    for (int k = 0; k < GDEPTH; ++k) sv[k] = 0.f;
    int eu = __builtin_amdgcn_readfirstlane(rowptr[node]);
    int endu = __builtin_amdgcn_readfirstlane(rowptr[node + 1]);
    for (int e = eu; e < endu; e += GDEPTH) {
        int raw[GDEPTH];
        #pragma unroll
        for (int k = 0; k < GDEPTH; ++k) raw[k] = ssort[e + k];
        #pragma unroll
        for (int k = 0; k < GDEPTH; ++k) {
            int ix = (e + k < endu) ? raw[k] : raw[0];
            float v = h2s[(size_t)ix * OUTC + lc];
            sv[k] += (e + k < endu) ? v : 0.f;
        }
    }
    float s = s0;
    #pragma unroll
    for (int k = 0; k < GDEPTH; ++k) s += sv[k];
    float v = act ? (dinv[node] * s + b2[lane]) : -INFINITY;
    float m = v;
    #pragma unroll
    for (int o = 32; o; o >>= 1) m = fmaxf(m, __shfl_xor(m, o));
    float p = act ? expf(v - m) : 0.0f;
    float su = p;
    #pragma unroll
    for (int o = 32; o; o >>= 1) su += __shfl_xor(su, o);
    if (act) out[(size_t)node * OUTC + lane] = p / su;
}

static inline size_t alignup(size_t v) { return (v + 255) & ~(size_t)255; }

extern "C" void kernel_launch(void* const* d_in, const int* in_sizes, int n_in,
                              void* d_out, int out_size, void* d_ws, size_t ws_size,
                              hipStream_t stream) {
    const float* x  = (const float*)d_in[0];
    const int*   ei = (const int*)d_in[1];
    const float* W1 = (const float*)d_in[2];
    const float* b1 = (const float*)d_in[3];
    const float* W2 = (const float*)d_in[4];
    const float* b2 = (const float*)d_in[5];

    const int N = in_sizes[0] / IN_C;
    const int E = in_sizes[1] / 2;
    const int* src = ei;
    const int* dst = ei + E;

    char* w = (char*)d_ws;
    int* cnt    = (int*)w;   w += alignup((size_t)N * 4);
    int* fillc  = (int*)w;   w += alignup((size_t)N * 4);   // adjacent to cnt: single memset
    int* rowptr = (int*)w;   w += alignup((size_t)(N + 1) * 4);
    int* bsum   = (int*)w;   w += alignup(256 * 4);
    int* bpre   = (int*)w;   w += alignup(256 * 4);
    int* ssort  = (int*)w;   w += alignup((size_t)E * 4 + 256);  // +pad: scalar tail overreads
    float* dinv = (float*)w; w += alignup((size_t)N * 4);
    float* h1s  = (float*)w; w += alignup((size_t)N * HID * 4);
    float* h2s  = (float*)w; w += alignup((size_t)N * OUTC * 4);
    ushort* WThi = (ushort*)w; w += alignup((size_t)HID * IN_C * 2);
    ushort* WTlo = (ushort*)w; w += alignup((size_t)HID * IN_C * 2);

    hipMemsetAsync(cnt, 0, 2 * alignup((size_t)N * 4), stream);

    const int nb  = (N + 255) / 256;
    const int nbE = (E + 255) / 256;
    const int nbW = (HID * IN_C + 255) / 256;
    k_histsplit<<<nbE + nbW, 256, 0, stream>>>(dst, E, cnt, nbE, W1, WThi, WTlo);
    k_scan1<<<nb, 256, 0, stream>>>(cnt, N, rowptr, bsum);
    k_scan2<<<1, 256, 0, stream>>>(bsum, nb, bpre);
    k_scan3<<<nb, 256, 0, stream>>>(rowptr, bpre, cnt, dinv, N, E);
    k_fill <<<nbE, 256, 0, stream>>>(src, dst, E, rowptr, fillc, ssort);

    k_gemm1 <<<(N + 63) / 64, 256, 0, stream>>>(x, WThi, WTlo, dinv, h1s, N);
    k_agg1g2<<<2048, 256, 0, stream>>>(h1s, rowptr, ssort, dinv, b1, W2, h2s, N);
    k_agg2  <<<(N + 3) / 4, 256, 0, stream>>>(h2s, rowptr, ssort, dinv, b2, (float*)d_out, N);
}

// Round 7
// 154.702 us; speedup vs baseline: 1.6833x; 1.1778x over previous
//
#include <hip/hip_runtime.h>
#include <math.h>

#define IN_C 512
#define HID  64
#define OUTC 40

typedef __attribute__((ext_vector_type(8))) short bf16x8;
typedef __attribute__((ext_vector_type(4))) short bf16x4;
typedef __attribute__((ext_vector_type(4))) float f32x4;

#define GDEPTH 12

// ---------------- histogram of dst + per-edge rank (+ W1 split folded in) ----------------
// rank[i] = old count of dst[i]  — this IS the counting-sort ticket; k_fill
// no longer needs its own atomic.
__global__ void k_histsplit(const int* __restrict__ dst, int E,
                            int* __restrict__ cnt, int* __restrict__ rank,
                            int nbE2,
                            const float* __restrict__ W,
                            ushort* __restrict__ hi, ushort* __restrict__ lo) {
    if (blockIdx.x < (unsigned)nbE2) {
        int i = (blockIdx.x * blockDim.x + threadIdx.x) * 2;
        if (i < E) {
            if (i + 1 < E) {
                int2 d = *(const int2*)&dst[i];
                int r0 = atomicAdd(&cnt[d.x], 1);
                int r1 = atomicAdd(&cnt[d.y], 1);
                *(int2*)&rank[i] = make_int2(r0, r1);
            } else {
                rank[i] = atomicAdd(&cnt[dst[i]], 1);
            }
        }
    } else {
        // W1 split to hi/lo bf16, transposed: WT[c][k]
        int i = (blockIdx.x - nbE2) * blockDim.x + threadIdx.x;   // over 64*512
        if (i >= HID * IN_C) return;
        int c = i >> 9, k = i & 511;
        float v = W[(size_t)k * HID + c];
        uint ub = __float_as_uint(v);
        uint hb = ub & 0xFFFF0000u;
        float lf = v - __uint_as_float(hb);
        hi[i] = (ushort)(ub >> 16);
        lo[i] = (ushort)(__float_as_uint(lf) >> 16);
    }
}

// ---------------- prefix scan (3 kernels) ----------------
__global__ void k_scan1(const int* __restrict__ cnt, int N,
                        int* __restrict__ rowptr, int* __restrict__ bsum) {
    __shared__ int s[256];
    int t = threadIdx.x;
    int i = blockIdx.x * 256 + t;
    int v = (i < N) ? cnt[i] : 0;
    int x = v;
    s[t] = x; __syncthreads();
    #pragma unroll
    for (int o = 1; o < 256; o <<= 1) {
        int y = (t >= o) ? s[t - o] : 0;
        __syncthreads();
        x += y; s[t] = x;
        __syncthreads();
    }
    if (i < N) rowptr[i] = x - v;          // exclusive
    if (t == 255) bsum[blockIdx.x] = x;    // block total
}

__global__ void k_scan2(const int* __restrict__ bsum, int nb, int* __restrict__ bpre) {
    __shared__ int s[256];
    int t = threadIdx.x;
    int v = (t < nb) ? bsum[t] : 0;
    int x = v;
    s[t] = x; __syncthreads();
    #pragma unroll
    for (int o = 1; o < 256; o <<= 1) {
        int y = (t >= o) ? s[t - o] : 0;
        __syncthreads();
        x += y; s[t] = x;
        __syncthreads();
    }
    bpre[t] = x - v;
}

__global__ void k_scan3(int* __restrict__ rowptr, const int* __restrict__ bpre,
                        const int* __restrict__ cnt, float* __restrict__ dinv,
                        int N, int E) {
    int i = blockIdx.x * blockDim.x + threadIdx.x;
    if (i < N) {
        rowptr[i] += bpre[i >> 8];
        dinv[i] = rsqrtf(1.0f + (float)cnt[i]);   // self-loop => deg >= 1
        if (i == 0) rowptr[N] = E;
    }
}

// ---------------- counting-sort scatter (atomic-free) ----------------
__global__ void k_fill(const int* __restrict__ src, const int* __restrict__ dst,
                       const int* __restrict__ rank, int E,
                       const int* __restrict__ rowptr, int* __restrict__ ssort) {
    int i = (blockIdx.x * blockDim.x + threadIdx.x) * 2;
    if (i >= E) return;
    if (i + 1 < E) {
        int2 d = *(const int2*)&dst[i];
        int2 s = *(const int2*)&src[i];
        int2 r = *(const int2*)&rank[i];
        int p0 = rowptr[d.x] + r.x;
        int p1 = rowptr[d.y] + r.y;
        ssort[p0] = s.x;
        ssort[p1] = s.y;
    } else {
        ssort[rowptr[dst[i]] + rank[i]] = src[i];
    }
}

// ---------------- GEMM1: LDS-staged split-bf16 MFMA ----------------
__global__ __launch_bounds__(256) void k_gemm1(const float* __restrict__ x,
                                               const ushort* __restrict__ WThi,
                                               const ushort* __restrict__ WTlo,
                                               const float* __restrict__ dinv,
                                               float* __restrict__ h1s, int N) {
    __shared__ ushort Ah[2][64 * 40], Al[2][64 * 40];
    __shared__ ushort Bh[2][64 * 40], Bl[2][64 * 40];
    int t = threadIdx.x;
    int wid = t >> 6, lane = t & 63;
    int lr = lane & 15, lko = lane >> 4;
    int wm = wid >> 1, wn = wid & 1;
    int row0 = blockIdx.x * 64;

    int srow = t >> 3, sf4 = t & 7;
    int scol = t >> 2, sseg = t & 3;
    int xr0 = row0 + srow;      if (xr0 >= N) xr0 = N - 1;
    int xr1 = row0 + srow + 32; if (xr1 >= N) xr1 = N - 1;
    const float* xp0 = x + (size_t)xr0 * IN_C + sf4 * 4;
    const float* xp1 = x + (size_t)xr1 * IN_C + sf4 * 4;
    const ushort* bhp = WThi + (size_t)scol * IN_C + sseg * 8;
    const ushort* blp = WTlo + (size_t)scol * IN_C + sseg * 8;

    f32x4 acc[2][2] = {};
    float4 xrg[2];
    bf16x8 bhr, blr;

    auto stage_load = [&](int kt) {
        xrg[0] = *(const float4*)(xp0 + kt);
        xrg[1] = *(const float4*)(xp1 + kt);
        bhr = *(const bf16x8*)(bhp + kt);
        blr = *(const bf16x8*)(blp + kt);
    };
    auto stage_write = [&](int b) {
        #pragma unroll
        for (int p = 0; p < 2; ++p) {
            float xv[4];
            *(float4*)xv = xrg[p];
            bf16x4 h, l;
            #pragma unroll
            for (int j = 0; j < 4; ++j) {
                uint ub = __float_as_uint(xv[j]);
                float hf = __uint_as_float(ub & 0xFFFF0000u);
                float lf = xv[j] - hf;
                h[j] = (short)(ub >> 16);
                l[j] = (short)(__float_as_uint(lf) >> 16);
            }
            int row = srow + p * 32;
            *(bf16x4*)&Ah[b][row * 40 + sf4 * 4] = h;
            *(bf16x4*)&Al[b][row * 40 + sf4 * 4] = l;
        }
        *(bf16x8*)&Bh[b][scol * 40 + sseg * 8] = bhr;
        *(bf16x8*)&Bl[b][scol * 40 + sseg * 8] = blr;
    };
    auto compute = [&](int b) {
        bf16x8 afh[2], afl[2], bfh[2], bfl[2];
        #pragma unroll
        for (int mf = 0; mf < 2; ++mf) {
            int row = wm * 32 + mf * 16 + lr;
            afh[mf] = *(const bf16x8*)&Ah[b][row * 40 + lko * 8];
            afl[mf] = *(const bf16x8*)&Al[b][row * 40 + lko * 8];
        }
        #pragma unroll
        for (int nf = 0; nf < 2; ++nf) {
            int col = wn * 32 + nf * 16 + lr;
            bfh[nf] = *(const bf16x8*)&Bh[b][col * 40 + lko * 8];
            bfl[nf] = *(const bf16x8*)&Bl[b][col * 40 + lko * 8];
        }
        #pragma unroll
        for (int mf = 0; mf < 2; ++mf)
            #pragma unroll
            for (int nf = 0; nf < 2; ++nf) {
                acc[mf][nf] = __builtin_amdgcn_mfma_f32_16x16x32_bf16(afh[mf], bfh[nf], acc[mf][nf], 0, 0, 0);
                acc[mf][nf] = __builtin_amdgcn_mfma_f32_16x16x32_bf16(afl[mf], bfh[nf], acc[mf][nf], 0, 0, 0);
                acc[mf][nf] = __builtin_amdgcn_mfma_f32_16x16x32_bf16(afh[mf], bfl[nf], acc[mf][nf], 0, 0, 0);
            }
    };

    stage_load(0);
    stage_write(0);
    __syncthreads();

    #pragma unroll
    for (int i = 0; i < 16; ++i) {
        if (i < 15) stage_load((i + 1) * 32);
        compute(i & 1);
        if (i < 15) stage_write((i + 1) & 1);
        __syncthreads();
    }

    #pragma unroll
    for (int mf = 0; mf < 2; ++mf)
        #pragma unroll
        for (int r = 0; r < 4; ++r) {
            int orow = row0 + wm * 32 + mf * 16 + lko * 4 + r;
            if (orow < N) {
                float dv = dinv[orow];
                #pragma unroll
                for (int nf = 0; nf < 2; ++nf)
                    h1s[(size_t)orow * HID + wn * 32 + nf * 16 + lr] = dv * acc[mf][nf][r];
            }
        }
}

// ---------------- fused agg1 + gemm2 ----------------
__global__ __launch_bounds__(256) void k_agg1g2(const float* __restrict__ h1s,
                                                const int* __restrict__ rowptr,
                                                const int* __restrict__ ssort,
                                                const float* __restrict__ dinv,
                                                const float* __restrict__ b1,
                                                const float* __restrict__ W2,
                                                float* __restrict__ h2s, int N) {
    __shared__ float wl[HID * OUTC];      // 2560 floats = 10.24 KB
    int t = threadIdx.x;
    #pragma unroll
    for (int q0 = 0; q0 < 3; ++q0) {
        int q = t + q0 * 256;
        if (q < 640) *(float4*)&wl[q * 4] = *(const float4*)&W2[q * 4];
    }
    __syncthreads();

    int lane = t & 63;
    int wq = t >> 6;
    int lc = lane < OUTC ? lane : 0;
    float bias = b1[lane];
    int nq = (N + 3) >> 2;

    for (int q = blockIdx.x; q < nq; q += gridDim.x) {
        int node = q * 4 + wq;
        if (node >= N) continue;
        float s0 = h1s[(size_t)node * HID + lane];   // self-loop term
        float sv[GDEPTH];
        #pragma unroll
        for (int k = 0; k < GDEPTH; ++k) sv[k] = 0.f;
        int eu = __builtin_amdgcn_readfirstlane(rowptr[node]);
        int endu = __builtin_amdgcn_readfirstlane(rowptr[node + 1]);
        for (int e = eu; e < endu; e += GDEPTH) {
            int raw[GDEPTH];
            #pragma unroll
            for (int k = 0; k < GDEPTH; ++k) raw[k] = ssort[e + k];  // scalar s_load path
            #pragma unroll
            for (int k = 0; k < GDEPTH; ++k) {
                int ix = (e + k < endu) ? raw[k] : raw[0];
                float v = h1s[(size_t)ix * HID + lane];
                sv[k] += (e + k < endu) ? v : 0.f;
            }
        }
        float s = s0;
        #pragma unroll
        for (int k = 0; k < GDEPTH; ++k) s += sv[k];
        float dv = dinv[node];
        float a = fmaxf(fmaf(dv, s, bias), 0.0f);
        // in-wave gemm2: h2[c] = sum_k a[k] * W2[k][c]
        float acc = 0.f;
        #pragma unroll
        for (int k = 0; k < HID; ++k) {
            float ak = __uint_as_float(__builtin_amdgcn_readlane(__float_as_uint(a), k));
            acc = fmaf(ak, wl[k * OUTC + lc], acc);
        }
        if (lane < OUTC) h2s[(size_t)node * OUTC + lane] = dv * acc;
    }
}

// ---------------- agg2 + bias + softmax ----------------
__global__ __launch_bounds__(256) void k_agg2(const float* __restrict__ h2s,
                                              const int* __restrict__ rowptr,
                                              const int* __restrict__ ssort,
                                              const float* __restrict__ dinv,
                                              const float* __restrict__ b2,
                                              float* __restrict__ out, int N) {
    int lane = threadIdx.x & 63;
    int node = blockIdx.x * 4 + (threadIdx.x >> 6);
    if (node >= N) return;
    bool act = lane < OUTC;
    int lc = act ? lane : 0;
    float s0 = h2s[(size_t)node * OUTC + lc];
    float sv[GDEPTH];
    #pragma unroll
    for (int k = 0; k < GDEPTH; ++k) sv[k] = 0.f;
    int eu = __builtin_amdgcn_readfirstlane(rowptr[node]);
    int endu = __builtin_amdgcn_readfirstlane(rowptr[node + 1]);
    for (int e = eu; e < endu; e += GDEPTH) {
        int raw[GDEPTH];
        #pragma unroll
        for (int k = 0; k < GDEPTH; ++k) raw[k] = ssort[e + k];
        #pragma unroll
        for (int k = 0; k < GDEPTH; ++k) {
            int ix = (e + k < endu) ? raw[k] : raw[0];
            float v = h2s[(size_t)ix * OUTC + lc];
            sv[k] += (e + k < endu) ? v : 0.f;
        }
    }
    float s = s0;
    #pragma unroll
    for (int k = 0; k < GDEPTH; ++k) s += sv[k];
    float v = act ? (dinv[node] * s + b2[lane]) : -INFINITY;
    float m = v;
    #pragma unroll
    for (int o = 32; o; o >>= 1) m = fmaxf(m, __shfl_xor(m, o));
    float p = act ? expf(v - m) : 0.0f;
    float su = p;
    #pragma unroll
    for (int o = 32; o; o >>= 1) su += __shfl_xor(su, o);
    if (act) out[(size_t)node * OUTC + lane] = p / su;
}

static inline size_t alignup(size_t v) { return (v + 255) & ~(size_t)255; }

extern "C" void kernel_launch(void* const* d_in, const int* in_sizes, int n_in,
                              void* d_out, int out_size, void* d_ws, size_t ws_size,
                              hipStream_t stream) {
    const float* x  = (const float*)d_in[0];
    const int*   ei = (const int*)d_in[1];
    const float* W1 = (const float*)d_in[2];
    const float* b1 = (const float*)d_in[3];
    const float* W2 = (const float*)d_in[4];
    const float* b2 = (const float*)d_in[5];

    const int N = in_sizes[0] / IN_C;
    const int E = in_sizes[1] / 2;
    const int* src = ei;
    const int* dst = ei + E;

    char* w = (char*)d_ws;
    int* cnt    = (int*)w;   w += alignup((size_t)N * 4);
    int* rank   = (int*)w;   w += alignup((size_t)E * 4 + 256);
    int* rowptr = (int*)w;   w += alignup((size_t)(N + 1) * 4);
    int* bsum   = (int*)w;   w += alignup(256 * 4);
    int* bpre   = (int*)w;   w += alignup(256 * 4);
    int* ssort  = (int*)w;   w += alignup((size_t)E * 4 + 256);  // +pad: scalar tail overreads
    float* dinv = (float*)w; w += alignup((size_t)N * 4);
    float* h1s  = (float*)w; w += alignup((size_t)N * HID * 4);
    float* h2s  = (float*)w; w += alignup((size_t)N * OUTC * 4);
    ushort* WThi = (ushort*)w; w += alignup((size_t)HID * IN_C * 2);
    ushort* WTlo = (ushort*)w; w += alignup((size_t)HID * IN_C * 2);

    hipMemsetAsync(cnt, 0, alignup((size_t)N * 4), stream);

    const int nb   = (N + 255) / 256;
    const int nbE2 = (E / 2 + 255) / 256;
    const int nbW  = (HID * IN_C + 255) / 256;
    k_histsplit<<<nbE2 + nbW, 256, 0, stream>>>(dst, E, cnt, rank, nbE2, W1, WThi, WTlo);
    k_scan1<<<nb, 256, 0, stream>>>(cnt, N, rowptr, bsum);
    k_scan2<<<1, 256, 0, stream>>>(bsum, nb, bpre);
    k_scan3<<<nb, 256, 0, stream>>>(rowptr, bpre, cnt, dinv, N, E);
    k_fill <<<nbE2, 256, 0, stream>>>(src, dst, rank, E, rowptr, ssort);

    k_gemm1 <<<(N + 63) / 64, 256, 0, stream>>>(x, WThi, WTlo, dinv, h1s, N);
    k_agg1g2<<<2048, 256, 0, stream>>>(h1s, rowptr, ssort, dinv, b1, W2, h2s, N);
    k_agg2  <<<(N + 3) / 4, 256, 0, stream>>>(h2s, rowptr, ssort, dinv, b2, (float*)d_out, N);
}

// Round 8
// 147.566 us; speedup vs baseline: 1.7647x; 1.0484x over previous
//
#include <hip/hip_runtime.h>
#include <math.h>

#define IN_C 512
#define HID  64
#define OUTC 40

typedef __attribute__((ext_vector_type(8))) short bf16x8;
typedef __attribute__((ext_vector_type(4))) short bf16x4;
typedef __attribute__((ext_vector_type(4))) float f32x4;

#define GDEPTH 12

__device__ __forceinline__ ushort f2bf(float f) {          // RNE
    uint u = __float_as_uint(f);
    u += 0x7FFFu + ((u >> 16) & 1u);
    return (ushort)(u >> 16);
}
__device__ __forceinline__ float bf2f(ushort s) {
    return __uint_as_float(((uint)s) << 16);
}

// ---------------- histogram of dst + per-edge rank (+ W1 split folded in) ----------------
__global__ void k_histsplit(const int* __restrict__ dst, int E,
                            int* __restrict__ cnt, int* __restrict__ rank,
                            int nbE2,
                            const float* __restrict__ W,
                            ushort* __restrict__ hi, ushort* __restrict__ lo) {
    if (blockIdx.x < (unsigned)nbE2) {
        int i = (blockIdx.x * blockDim.x + threadIdx.x) * 2;
        if (i < E) {
            if (i + 1 < E) {
                int2 d = *(const int2*)&dst[i];
                int r0 = atomicAdd(&cnt[d.x], 1);
                int r1 = atomicAdd(&cnt[d.y], 1);
                *(int2*)&rank[i] = make_int2(r0, r1);
            } else {
                rank[i] = atomicAdd(&cnt[dst[i]], 1);
            }
        }
    } else {
        // W1 split to hi/lo bf16, transposed: WT[c][k]
        int i = (blockIdx.x - nbE2) * blockDim.x + threadIdx.x;   // over 64*512
        if (i >= HID * IN_C) return;
        int c = i >> 9, k = i & 511;
        float v = W[(size_t)k * HID + c];
        uint ub = __float_as_uint(v);
        uint hb = ub & 0xFFFF0000u;
        float lf = v - __uint_as_float(hb);
        hi[i] = (ushort)(ub >> 16);
        lo[i] = (ushort)(__float_as_uint(lf) >> 16);
    }
}

// ---------------- prefix scan ----------------
__global__ void k_scan1(const int* __restrict__ cnt, int N,
                        int* __restrict__ rowptr, int* __restrict__ bsum) {
    __shared__ int s[256];
    int t = threadIdx.x;
    int i = blockIdx.x * 256 + t;
    int v = (i < N) ? cnt[i] : 0;
    int x = v;
    s[t] = x; __syncthreads();
    #pragma unroll
    for (int o = 1; o < 256; o <<= 1) {
        int y = (t >= o) ? s[t - o] : 0;
        __syncthreads();
        x += y; s[t] = x;
        __syncthreads();
    }
    if (i < N) rowptr[i] = x - v;          // exclusive
    if (t == 255) bsum[blockIdx.x] = x;    // block total
}

// scan2+scan3 fused: every block redundantly scans bsum (nb<=256), then
// applies its own block prefix + writes dinv.
__global__ void k_scan23(int* __restrict__ rowptr, const int* __restrict__ bsum,
                         const int* __restrict__ cnt, float* __restrict__ dinv,
                         int N, int E, int nb) {
    __shared__ int s[256];
    int t = threadIdx.x;
    int v = (t < nb) ? bsum[t] : 0;
    int x = v;
    s[t] = x; __syncthreads();
    #pragma unroll
    for (int o = 1; o < 256; o <<= 1) {
        int y = (t >= o) ? s[t - o] : 0;
        __syncthreads();
        x += y; s[t] = x;
        __syncthreads();
    }
    int bpre = (blockIdx.x > 0) ? s[blockIdx.x - 1] : 0;
    int i = blockIdx.x * 256 + t;
    if (i < N) {
        rowptr[i] += bpre;
        dinv[i] = rsqrtf(1.0f + (float)cnt[i]);   // self-loop => deg >= 1
        if (i == 0) rowptr[N] = E;
    }
}

// ---------------- counting-sort scatter (atomic-free) ----------------
__global__ void k_fill(const int* __restrict__ src, const int* __restrict__ dst,
                       const int* __restrict__ rank, int E,
                       const int* __restrict__ rowptr, int* __restrict__ ssort) {
    int i = (blockIdx.x * blockDim.x + threadIdx.x) * 2;
    if (i >= E) return;
    if (i + 1 < E) {
        int2 d = *(const int2*)&dst[i];
        int2 s = *(const int2*)&src[i];
        int2 r = *(const int2*)&rank[i];
        int p0 = rowptr[d.x] + r.x;
        int p1 = rowptr[d.y] + r.y;
        ssort[p0] = s.x;
        ssort[p1] = s.y;
    } else {
        ssort[rowptr[dst[i]] + rank[i]] = src[i];
    }
}

// ---------------- GEMM1: LDS-staged split-bf16 MFMA, bf16 output ----------------
__global__ __launch_bounds__(256) void k_gemm1(const float* __restrict__ x,
                                               const ushort* __restrict__ WThi,
                                               const ushort* __restrict__ WTlo,
                                               const float* __restrict__ dinv,
                                               ushort* __restrict__ h1s, int N) {
    __shared__ ushort Ah[2][64 * 40], Al[2][64 * 40];
    __shared__ ushort Bh[2][64 * 40], Bl[2][64 * 40];
    int t = threadIdx.x;
    int wid = t >> 6, lane = t & 63;
    int lr = lane & 15, lko = lane >> 4;
    int wm = wid >> 1, wn = wid & 1;
    int row0 = blockIdx.x * 64;

    int srow = t >> 3, sf4 = t & 7;
    int scol = t >> 2, sseg = t & 3;
    int xr0 = row0 + srow;      if (xr0 >= N) xr0 = N - 1;
    int xr1 = row0 + srow + 32; if (xr1 >= N) xr1 = N - 1;
    const float* xp0 = x + (size_t)xr0 * IN_C + sf4 * 4;
    const float* xp1 = x + (size_t)xr1 * IN_C + sf4 * 4;
    const ushort* bhp = WThi + (size_t)scol * IN_C + sseg * 8;
    const ushort* blp = WTlo + (size_t)scol * IN_C + sseg * 8;

    f32x4 acc[2][2] = {};
    float4 xrg[2];
    bf16x8 bhr, blr;

    auto stage_load = [&](int kt) {
        xrg[0] = *(const float4*)(xp0 + kt);
        xrg[1] = *(const float4*)(xp1 + kt);
        bhr = *(const bf16x8*)(bhp + kt);
        blr = *(const bf16x8*)(blp + kt);
    };
    auto stage_write = [&](int b) {
        #pragma unroll
        for (int p = 0; p < 2; ++p) {
            float xv[4];
            *(float4*)xv = xrg[p];
            bf16x4 h, l;
            #pragma unroll
            for (int j = 0; j < 4; ++j) {
                uint ub = __float_as_uint(xv[j]);
                float hf = __uint_as_float(ub & 0xFFFF0000u);
                float lf = xv[j] - hf;
                h[j] = (short)(ub >> 16);
                l[j] = (short)(__float_as_uint(lf) >> 16);
            }
            int row = srow + p * 32;
            *(bf16x4*)&Ah[b][row * 40 + sf4 * 4] = h;
            *(bf16x4*)&Al[b][row * 40 + sf4 * 4] = l;
        }
        *(bf16x8*)&Bh[b][scol * 40 + sseg * 8] = bhr;
        *(bf16x8*)&Bl[b][scol * 40 + sseg * 8] = blr;
    };
    auto compute = [&](int b) {
        bf16x8 afh[2], afl[2], bfh[2], bfl[2];
        #pragma unroll
        for (int mf = 0; mf < 2; ++mf) {
            int row = wm * 32 + mf * 16 + lr;
            afh[mf] = *(const bf16x8*)&Ah[b][row * 40 + lko * 8];
            afl[mf] = *(const bf16x8*)&Al[b][row * 40 + lko * 8];
        }
        #pragma unroll
        for (int nf = 0; nf < 2; ++nf) {
            int col = wn * 32 + nf * 16 + lr;
            bfh[nf] = *(const bf16x8*)&Bh[b][col * 40 + lko * 8];
            bfl[nf] = *(const bf16x8*)&Bl[b][col * 40 + lko * 8];
        }
        #pragma unroll
        for (int mf = 0; mf < 2; ++mf)
            #pragma unroll
            for (int nf = 0; nf < 2; ++nf) {
                acc[mf][nf] = __builtin_amdgcn_mfma_f32_16x16x32_bf16(afh[mf], bfh[nf], acc[mf][nf], 0, 0, 0);
                acc[mf][nf] = __builtin_amdgcn_mfma_f32_16x16x32_bf16(afl[mf], bfh[nf], acc[mf][nf], 0, 0, 0);
                acc[mf][nf] = __builtin_amdgcn_mfma_f32_16x16x32_bf16(afh[mf], bfl[nf], acc[mf][nf], 0, 0, 0);
            }
    };

    stage_load(0);
    stage_write(0);
    __syncthreads();

    #pragma unroll
    for (int i = 0; i < 16; ++i) {
        if (i < 15) stage_load((i + 1) * 32);
        compute(i & 1);
        if (i < 15) stage_write((i + 1) & 1);
        __syncthreads();
    }

    #pragma unroll
    for (int mf = 0; mf < 2; ++mf)
        #pragma unroll
        for (int r = 0; r < 4; ++r) {
            int orow = row0 + wm * 32 + mf * 16 + lko * 4 + r;
            if (orow < N) {
                float dv = dinv[orow];
                #pragma unroll
                for (int nf = 0; nf < 2; ++nf)
                    h1s[(size_t)orow * HID + wn * 32 + nf * 16 + lr] = f2bf(dv * acc[mf][nf][r]);
            }
        }
}

// ---------------- fused agg1 + gemm2 (bf16 h1s gather, bf16 h2s out) ----------------
__global__ __launch_bounds__(256) void k_agg1g2(const ushort* __restrict__ h1s,
                                                const int* __restrict__ rowptr,
                                                const int* __restrict__ ssort,
                                                const float* __restrict__ dinv,
                                                const float* __restrict__ b1,
                                                const float* __restrict__ W2,
                                                ushort* __restrict__ h2s, int N) {
    __shared__ float wl[HID * OUTC];      // 2560 floats = 10.24 KB
    int t = threadIdx.x;
    #pragma unroll
    for (int q0 = 0; q0 < 3; ++q0) {
        int q = t + q0 * 256;
        if (q < 640) *(float4*)&wl[q * 4] = *(const float4*)&W2[q * 4];
    }
    __syncthreads();

    int lane = t & 63;
    int wq = t >> 6;
    int lc = lane < OUTC ? lane : 0;
    float bias = b1[lane];
    int nq = (N + 3) >> 2;

    for (int q = blockIdx.x; q < nq; q += gridDim.x) {
        int node = q * 4 + wq;
        if (node >= N) continue;
        float s0 = bf2f(h1s[(size_t)node * HID + lane]);   // self-loop term
        float sv[GDEPTH];
        #pragma unroll
        for (int k = 0; k < GDEPTH; ++k) sv[k] = 0.f;
        int eu = __builtin_amdgcn_readfirstlane(rowptr[node]);
        int endu = __builtin_amdgcn_readfirstlane(rowptr[node + 1]);
        for (int e = eu; e < endu; e += GDEPTH) {
            int raw[GDEPTH];
            #pragma unroll
            for (int k = 0; k < GDEPTH; ++k) raw[k] = ssort[e + k];  // scalar s_load path
            #pragma unroll
            for (int k = 0; k < GDEPTH; ++k) {
                int ix = (e + k < endu) ? raw[k] : raw[0];
                float v = bf2f(h1s[(size_t)ix * HID + lane]);
                sv[k] += (e + k < endu) ? v : 0.f;
            }
        }
        float s = s0;
        #pragma unroll
        for (int k = 0; k < GDEPTH; ++k) s += sv[k];
        float dv = dinv[node];
        float a = fmaxf(fmaf(dv, s, bias), 0.0f);
        // in-wave gemm2: h2[c] = sum_k a[k] * W2[k][c]
        float acc = 0.f;
        #pragma unroll
        for (int k = 0; k < HID; ++k) {
            float ak = __uint_as_float(__builtin_amdgcn_readlane(__float_as_uint(a), k));
            acc = fmaf(ak, wl[k * OUTC + lc], acc);
        }
        if (lane < OUTC) h2s[(size_t)node * OUTC + lane] = f2bf(dv * acc);
    }
}

// ---------------- agg2 + bias + softmax (bf16 h2s gather) ----------------
__global__ __launch_bounds__(256) void k_agg2(const ushort* __restrict__ h2s,
                                              const int* __restrict__ rowptr,
                                              const int* __restrict__ ssort,
                                              const float* __restrict__ dinv,
                                              const float* __restrict__ b2,
                                              float* __restrict__ out, int N) {
    int lane = threadIdx.x & 63;
    int node = blockIdx.x * 4 + (threadIdx.x >> 6);
    if (node >= N) return;
    bool act = lane < OUTC;
    int lc = act ? lane : 0;
    float s0 = bf2f(h2s[(size_t)node * OUTC + lc]);
    float sv[GDEPTH];
    #pragma unroll
    for (int k = 0; k < GDEPTH; ++k) sv[k] = 0.f;
    int eu = __builtin_amdgcn_readfirstlane(rowptr[node]);
    int endu = __builtin_amdgcn_readfirstlane(rowptr[node + 1]);
    for (int e = eu; e < endu; e += GDEPTH) {
        int raw[GDEPTH];
        #pragma unroll
        for (int k = 0; k < GDEPTH; ++k) raw[k] = ssort[e + k];
        #pragma unroll
        for (int k = 0; k < GDEPTH; ++k) {
            int ix = (e + k < endu) ? raw[k] : raw[0];
            float v = bf2f(h2s[(size_t)ix * OUTC + lc]);
            sv[k] += (e + k < endu) ? v : 0.f;
        }
    }
    float s = s0;
    #pragma unroll
    for (int k = 0; k < GDEPTH; ++k) s += sv[k];
    float v = act ? (dinv[node] * s + b2[lane]) : -INFINITY;
    float m = v;
    #pragma unroll
    for (int o = 32; o; o >>= 1) m = fmaxf(m, __shfl_xor(m, o));
    float p = act ? expf(v - m) : 0.0f;
    float su = p;
    #pragma unroll
    for (int o = 32; o; o >>= 1) su += __shfl_xor(su, o);
    if (act) out[(size_t)node * OUTC + lane] = p / su;
}

static inline size_t alignup(size_t v) { return (v + 255) & ~(size_t)255; }

extern "C" void kernel_launch(void* const* d_in, const int* in_sizes, int n_in,
                              void* d_out, int out_size, void* d_ws, size_t ws_size,
                              hipStream_t stream) {
    const float* x  = (const float*)d_in[0];
    const int*   ei = (const int*)d_in[1];
    const float* W1 = (const float*)d_in[2];
    const float* b1 = (const float*)d_in[3];
    const float* W2 = (const float*)d_in[4];
    const float* b2 = (const float*)d_in[5];

    const int N = in_sizes[0] / IN_C;
    const int E = in_sizes[1] / 2;
    const int* src = ei;
    const int* dst = ei + E;

    char* w = (char*)d_ws;
    int* cnt    = (int*)w;   w += alignup((size_t)N * 4);
    int* rank   = (int*)w;   w += alignup((size_t)E * 4 + 256);
    int* rowptr = (int*)w;   w += alignup((size_t)(N + 1) * 4);
    int* bsum   = (int*)w;   w += alignup(256 * 4);
    int* ssort  = (int*)w;   w += alignup((size_t)E * 4 + 256);  // +pad: scalar tail overreads
    float* dinv = (float*)w; w += alignup((size_t)N * 4);
    ushort* h1s = (ushort*)w; w += alignup((size_t)N * HID * 2);
    ushort* h2s = (ushort*)w; w += alignup((size_t)N * OUTC * 2);
    ushort* WThi = (ushort*)w; w += alignup((size_t)HID * IN_C * 2);
    ushort* WTlo = (ushort*)w; w += alignup((size_t)HID * IN_C * 2);

    hipMemsetAsync(cnt, 0, alignup((size_t)N * 4), stream);

    const int nb   = (N + 255) / 256;
    const int nbE2 = (E / 2 + 255) / 256;
    const int nbW  = (HID * IN_C + 255) / 256;
    k_histsplit<<<nbE2 + nbW, 256, 0, stream>>>(dst, E, cnt, rank, nbE2, W1, WThi, WTlo);
    k_scan1 <<<nb, 256, 0, stream>>>(cnt, N, rowptr, bsum);
    k_scan23<<<nb, 256, 0, stream>>>(rowptr, bsum, cnt, dinv, N, E, nb);
    k_fill  <<<nbE2, 256, 0, stream>>>(src, dst, rank, E, rowptr, ssort);

    k_gemm1 <<<(N + 63) / 64, 256, 0, stream>>>(x, WThi, WTlo, dinv, h1s, N);
    k_agg1g2<<<2048, 256, 0, stream>>>(h1s, rowptr, ssort, dinv, b1, W2, h2s, N);
    k_agg2  <<<(N + 3) / 4, 256, 0, stream>>>(h2s, rowptr, ssort, dinv, b2, (float*)d_out, N);
}